// Round 12
// baseline (178.750 us; speedup 1.0000x reference)
//
#include <hip/hip_runtime.h>
#include <cmath>

#define NB 2
#define SEQ 2048
#define DIM 512
#define NH 8
#define DEPTH 64
#define NT (SEQ / 64)

typedef _Float16 f16_t;
typedef _Float16 f16x4 __attribute__((ext_vector_type(4)));
typedef _Float16 f16x8 __attribute__((ext_vector_type(8)));
typedef float f32x4 __attribute__((ext_vector_type(4)));

#define MFMA16(a, b, c) __builtin_amdgcn_mfma_f32_16x16x32_f16((a), (b), (c), 0, 0, 0)

// ---------------------------------------------------------------------------
// Kernel 1: prep — W^T as fp16 (bx<256) + X -> fp16 (bx>=256). grid 1280.
// ---------------------------------------------------------------------------
__global__ __launch_bounds__(256) void prep_kernel(
    const float* __restrict__ X,
    const float* __restrict__ Wq, const float* __restrict__ Wk,
    const float* __restrict__ Wv, const float* __restrict__ Wo,
    f16_t* __restrict__ wt, f16_t* __restrict__ wot, f16_t* __restrict__ xh)
{
    const int bx = blockIdx.x;
    if (bx >= 256) {
        const size_t i = ((size_t)(bx - 256) * 256 + threadIdx.x) * 8;
        const f32x4 a = *(const f32x4*)(X + i);
        const f32x4 b = *(const f32x4*)(X + i + 4);
        f16x8 o;
        #pragma unroll
        for (int j = 0; j < 4; ++j) { o[j] = (f16_t)a[j]; o[j+4] = (f16_t)b[j]; }
        *(f16x8*)(xh + i) = o;
        return;
    }
    __shared__ float Ws[64][68];
    const int z  = bx >> 6;
    const int kt = (bx >> 3) & 7;
    const int nt = bx & 7;
    const float* W = (z == 0) ? Wq : (z == 1) ? Wk : (z == 2) ? Wv : Wo;
    const int k0 = kt * 64, n0 = nt * 64;
    const int t = threadIdx.x;
    {
        const int r = t >> 2, c0 = (t & 3) * 16;
        #pragma unroll
        for (int j = 0; j < 4; ++j)
            *(f32x4*)&Ws[r][c0 + j*4] =
                *(const f32x4*)&W[(size_t)(k0 + r) * DIM + n0 + c0 + j*4];
    }
    __syncthreads();
    const int n = t >> 2, kc = (t & 3) * 16;
    f16x8 b0, b1;
    #pragma unroll
    for (int j = 0; j < 8; ++j) {
        b0[j] = (f16_t)Ws[kc + j][n];
        b1[j] = (f16_t)Ws[kc + 8 + j][n];
    }
    f16_t* dst = (z < 3) ? (wt + ((size_t)(z * DIM + n0 + n)) * DIM + k0 + kc)
                         : (wot + (size_t)(n0 + n) * DIM + k0 + kc);
    *(f16x8*)dst = b0;
    *(f16x8*)(dst + 8) = b1;
}

// ---------------------------------------------------------------------------
// Kernel 2: QKV projection, direct-global MFMA GEMM on fp16 X.
// grid 384 (32 mb x 12 nb), block 256 (4 waves 2x2, 64x64 per wave)
// ---------------------------------------------------------------------------
__global__ __launch_bounds__(256, 2) void qkv_gemm_kernel(
    const f16_t* __restrict__ xh, const f16_t* __restrict__ wt,
    const float* __restrict__ bq, const float* __restrict__ bk,
    const float* __restrict__ bv,
    f16_t* __restrict__ q_h, f16_t* __restrict__ k_h, f16_t* __restrict__ v_t)
{
    const int bx = blockIdx.x;
    const int mb = bx & 31, nb = bx >> 5;
    const int tid = threadIdx.x;
    const int w = tid >> 6, lane = tid & 63, l15 = lane & 15, g4 = lane >> 4;
    const int mBase = mb * 128 + (w >> 1) * 64;
    const int nBase = nb * 128 + (w & 1) * 64;

    f32x4 acc[4][4];
    #pragma unroll
    for (int i = 0; i < 4; ++i)
        #pragma unroll
        for (int j = 0; j < 4; ++j) acc[i][j] = (f32x4){0.f, 0.f, 0.f, 0.f};

    for (int k0 = 0; k0 < DIM; k0 += 64) {
        f16x8 ah[4][2];
        #pragma unroll
        for (int mt = 0; mt < 4; ++mt) {
            const f16_t* xr = xh + (size_t)(mBase + mt*16 + l15) * DIM + k0 + g4*8;
            ah[mt][0] = *(const f16x8*)xr;
            ah[mt][1] = *(const f16x8*)(xr + 32);
        }
        #pragma unroll
        for (int nt = 0; nt < 4; ++nt) {
            const f16_t* wr = wt + (size_t)(nBase + nt*16 + l15) * DIM + k0 + g4*8;
            #pragma unroll
            for (int kk = 0; kk < 2; ++kk) {
                f16x8 bw = *(const f16x8*)(wr + kk*32);
                #pragma unroll
                for (int mt = 0; mt < 4; ++mt)
                    acc[mt][nt] = MFMA16(ah[mt][kk], bw, acc[mt][nt]);
            }
        }
    }

    const int z = nb >> 2;
    const float* bias = (z == 0) ? bq : (z == 1) ? bk : bv;
    #pragma unroll
    for (int mt = 0; mt < 4; ++mt) {
        #pragma unroll
        for (int nt = 0; nt < 4; ++nt) {
            const int n = nBase + nt*16 + l15;
            const int col = n & 511;
            const int h = (n >> 6) & 7, d = n & 63;
            const float bb = bias[col];
            #pragma unroll
            for (int r = 0; r < 4; ++r) {
                const int m = mBase + mt*16 + g4*4 + r;
                const int b = m >> 11, s = m & (SEQ - 1);
                const int bh = b * NH + h;
                const float v = acc[mt][nt][r] + bb;
                if (z == 2) {
                    v_t[((size_t)bh * DEPTH + d) * SEQ + s] = (f16_t)v;
                } else {
                    const size_t o = ((size_t)bh * SEQ + s) * DEPTH + d;
                    if (z == 0) q_h[o] = (f16_t)v;
                    else        k_h[o] = (f16_t)v;
                }
            }
        }
    }
}

// ---------------------------------------------------------------------------
// Kernel 3: fused two-pass flash attention — r10 structure (champion), ONE
// change: attn stored DIRECTLY from pv registers inside the QK^T loop
// (16 q-rows x one full 64B line per instruction — r7/r8-proven amp=1.0),
// dropping the p_all readback reads and giving stores the whole PV phase
// to retire under before the barrier's vmcnt drain.
//  - no-max softmax; K/V/mask LDS double-buffered; __syncthreads per tile
//  - swapped-operand QK^T: mfma(K, Q) -> lane q = l15, keys = nt*16+g4*4+r
// grid 512 = 16 bh x 32 qt (XCD-swizzled), block 256 = 4 waves x 16 q-rows.
// ---------------------------------------------------------------------------
__global__ __launch_bounds__(256, 2) void attn_kernel(
    const f16_t* __restrict__ q_h, const f16_t* __restrict__ k_h,
    const f16_t* __restrict__ v_t, const float* __restrict__ mask,
    float* __restrict__ attn, f16_t* __restrict__ ctxf)
{
    __shared__ __align__(16) unsigned char smem[54784];
    f16_t (*Kh)[64][72] = (f16_t(*)[64][72])smem;            // 2 x 9216 B
    f16_t (*Vt)[64][72] = (f16_t(*)[64][72])(smem + 18432);  // 2 x 9216 B
    float (*p_all)[68]  = (float(*)[68])(smem + 36864);      // [64][68] f32
    float (*mask_s)[64] = (float(*)[64])(smem + 54272);      // 2 x 64 f32
    float (*cx)[68]     = (float(*)[68])smem;                // epilogue overlay

    const int tid = threadIdx.x;
    const int w = tid >> 6, lane = tid & 63;
    const int l15 = lane & 15, g4 = lane >> 4;
    const int rr = tid >> 2;              // staging row (key or d), 0..63
    const int cc = (tid & 3) << 4;        // staging col in f16, 0/16/32/48

    const int id  = blockIdx.x;
    const int nid = (id & 7) * 64 + (id >> 3);            // XCD-contiguous
    const int bh = nid >> 5, qt = nid & 31;
    const int b = bh >> 3, h = bh & 7;

    const size_t kvb = (size_t)bh * SEQ * DEPTH;
    const f16_t* khp = k_h + kvb;
    const f16_t* vtp = v_t + kvb;                         // [64][SEQ]
    const float* mp  = mask + b * SEQ;
    float* attn_p = attn + (size_t)bh * SEQ * SEQ;

    const int qb = qt * 64;
    const int qw = qb + w * 16;

    // Q fragment (B-operand: lane l15 = q row, g4*8 = d chunk)
    f16x8 qf0, qf1;
    {
        const f16_t* qr = q_h + kvb + (size_t)(qw + l15) * DEPTH + g4 * 8;
        qf0 = *(const f16x8*)qr;
        qf1 = *(const f16x8*)(qr + 32);
    }

    float l_r = 0.f;

    // ================= pass 0: sum(exp) (K + mask staged) =================
    {
        const f16_t* s0 = khp + (size_t)rr * DEPTH + cc;
        *(uint4*)&Kh[0][rr][cc]     = *(const uint4*)s0;
        *(uint4*)&Kh[0][rr][cc + 8] = *(const uint4*)(s0 + 8);
        if (tid < 64) mask_s[0][tid] = mp[tid];
    }
    __syncthreads();

    int cur = 0;
    for (int kt = 0; kt < NT; ++kt) {
        const bool have = (kt + 1) < NT;
        uint4 nk0, nk1; float nm = 0.f;
        if (have) {
            const f16_t* src = khp + (size_t)((kt+1)*64 + rr) * DEPTH + cc;
            nk0 = *(const uint4*)src;
            nk1 = *(const uint4*)(src + 8);
            if (tid < 64) nm = mp[(kt+1)*64 + tid];
        }

        #pragma unroll
        for (int nt = 0; nt < 4; ++nt) {
            const f16x8 a0 = *(const f16x8*)&Kh[cur][nt*16 + l15][g4*8];
            const f16x8 a1 = *(const f16x8*)&Kh[cur][nt*16 + l15][32 + g4*8];
            const f32x4 mb = *(const f32x4*)&mask_s[cur][nt*16 + g4*4];
            __builtin_amdgcn_s_setprio(1);
            f32x4 c = {0.f, 0.f, 0.f, 0.f};
            c = MFMA16(a0, qf0, c);
            c = MFMA16(a1, qf1, c);
            __builtin_amdgcn_s_setprio(0);
            #pragma unroll
            for (int r = 0; r < 4; ++r)
                l_r += __expf(c[r] * 0.125f + mb[r] * (-1e9f));
        }

        if (have) {
            *(uint4*)&Kh[cur ^ 1][rr][cc]     = nk0;
            *(uint4*)&Kh[cur ^ 1][rr][cc + 8] = nk1;
            if (tid < 64) mask_s[cur ^ 1][tid] = nm;
        }
        __syncthreads();
        cur ^= 1;
    }
    // deferred cross-lane reduce (sum is linear; no max tracking)
    l_r += __shfl_xor(l_r, 16);
    l_r += __shfl_xor(l_r, 32);
    const float invl = 1.0f / l_r;

    f32x4 cacc[4];
    #pragma unroll
    for (int nt = 0; nt < 4; ++nt) cacc[nt] = (f32x4){0.f, 0.f, 0.f, 0.f};

    // ================= pass 1: recompute, write attn, PV =================
    {
        const f16_t* s0 = khp + (size_t)rr * DEPTH + cc;
        *(uint4*)&Kh[0][rr][cc]     = *(const uint4*)s0;
        *(uint4*)&Kh[0][rr][cc + 8] = *(const uint4*)(s0 + 8);
        const f16_t* s1 = vtp + (size_t)rr * SEQ + cc;
        *(uint4*)&Vt[0][rr][cc]     = *(const uint4*)s1;
        *(uint4*)&Vt[0][rr][cc + 8] = *(const uint4*)(s1 + 8);
        if (tid < 64) mask_s[0][tid] = mp[tid];
    }
    __syncthreads();

    cur = 0;
    for (int kt = 0; kt < NT; ++kt) {
        const int kbase = kt * 64;
        const bool have = (kt + 1) < NT;
        uint4 nk0, nk1, nv0, nv1; float nm = 0.f;
        if (have) {
            const f16_t* srck = khp + (size_t)(kbase + 64 + rr) * DEPTH + cc;
            nk0 = *(const uint4*)srck;
            nk1 = *(const uint4*)(srck + 8);
            const f16_t* srcv = vtp + (size_t)rr * SEQ + kbase + 64 + cc;
            nv0 = *(const uint4*)srcv;
            nv1 = *(const uint4*)(srcv + 8);
            if (tid < 64) nm = mp[kbase + 64 + tid];
        }

        // ---- QK^T + p = exp(s)*invl; store attn DIRECT; stage P for PV ----
        #pragma unroll
        for (int nt = 0; nt < 4; ++nt) {
            const f16x8 a0 = *(const f16x8*)&Kh[cur][nt*16 + l15][g4*8];
            const f16x8 a1 = *(const f16x8*)&Kh[cur][nt*16 + l15][32 + g4*8];
            const f32x4 mb = *(const f32x4*)&mask_s[cur][nt*16 + g4*4];
            __builtin_amdgcn_s_setprio(1);
            f32x4 c = {0.f, 0.f, 0.f, 0.f};
            c = MFMA16(a0, qf0, c);
            c = MFMA16(a1, qf1, c);
            __builtin_amdgcn_s_setprio(0);
            f32x4 pv;
            #pragma unroll
            for (int r = 0; r < 4; ++r)
                pv[r] = __expf(c[r] * 0.125f + mb[r] * (-1e9f)) * invl;
            // direct store: per instruction, 16 q-rows x one full 64B line
            // (4 g4-lanes cover 16 consecutive floats per row) — amp=1.0 (r7/r8)
            __builtin_nontemporal_store(
                pv, (f32x4*)(attn_p + (size_t)(qw + l15) * SEQ + kbase + nt*16 + g4*4));
            *(f32x4*)&p_all[w*16 + l15][nt*16 + g4*4] = pv;
        }
        asm volatile("s_waitcnt lgkmcnt(0)" ::: "memory");
        __builtin_amdgcn_sched_barrier(0);

        // ---- PV: ctx^T[d][q] += V^T[d][k] P^T[k][q] ----
        #pragma unroll
        for (int kk = 0; kk < 2; ++kk) {
            const float* pr = &p_all[w*16 + l15][kk*32 + g4*8];
            const f32x4 p0 = *(const f32x4*)pr;
            const f32x4 p1 = *(const f32x4*)(pr + 4);
            f16x8 pf;
            #pragma unroll
            for (int j = 0; j < 4; ++j) { pf[j] = (f16_t)p0[j]; pf[j+4] = (f16_t)p1[j]; }
            __builtin_amdgcn_s_setprio(1);
            #pragma unroll
            for (int nt = 0; nt < 4; ++nt) {
                const f16x8 vf = *(const f16x8*)&Vt[cur][nt*16 + l15][kk*32 + g4*8];
                cacc[nt] = MFMA16(vf, pf, cacc[nt]);
            }
            __builtin_amdgcn_s_setprio(0);
        }

        if (have) {
            *(uint4*)&Kh[cur ^ 1][rr][cc]     = nk0;
            *(uint4*)&Kh[cur ^ 1][rr][cc + 8] = nk1;
            *(uint4*)&Vt[cur ^ 1][rr][cc]     = nv0;
            *(uint4*)&Vt[cur ^ 1][rr][cc + 8] = nv1;
            if (tid < 64) mask_s[cur ^ 1][tid] = nm;
        }
        __syncthreads();
        cur ^= 1;
    }

    // ---- epilogue: transpose ctx^T -> ctx via LDS ----
    #pragma unroll
    for (int nt = 0; nt < 4; ++nt)
        #pragma unroll
        for (int r = 0; r < 4; ++r)
            cx[nt*16 + g4*4 + r][w*16 + l15] = cacc[nt][r];
    __syncthreads();
    {
        const int q = tid >> 2, dc = (tid & 3) << 4;
        f16x8 o0, o1;
        #pragma unroll
        for (int j = 0; j < 8; ++j) {
            o0[j] = (f16_t)cx[dc + j][q];
            o1[j] = (f16_t)cx[dc + 8 + j][q];
        }
        f16_t* dst = ctxf + ((size_t)(b * SEQ) + qb + q) * DIM + h * 64 + dc;
        *(f16x8*)dst = o0;
        *(f16x8*)(dst + 8) = o1;
    }
}

// ---------------------------------------------------------------------------
// Kernel 4: out = ctx @ Wo + bo, direct-global MFMA (fp16).
// grid 256 (64 mb x 4 nb), block 256 (4 waves 2x2, 32x64 per wave)
// ---------------------------------------------------------------------------
__global__ __launch_bounds__(256, 2) void out_gemm_kernel(
    const f16_t* __restrict__ ctxf, const f16_t* __restrict__ wot,
    const float* __restrict__ bo, float* __restrict__ out)
{
    const int bx = blockIdx.x;
    const int mb = bx & 63, nb = bx >> 6;
    const int tid = threadIdx.x;
    const int w = tid >> 6, lane = tid & 63, l15 = lane & 15, g4 = lane >> 4;
    const int mBase = mb * 64 + (w >> 1) * 32;
    const int nBase = nb * 128 + (w & 1) * 64;

    f32x4 acc[2][4];
    #pragma unroll
    for (int i = 0; i < 2; ++i)
        #pragma unroll
        for (int j = 0; j < 4; ++j) acc[i][j] = (f32x4){0.f, 0.f, 0.f, 0.f};

    for (int k0 = 0; k0 < DIM; k0 += 64) {
        f16x8 ah[2][2];
        #pragma unroll
        for (int mt = 0; mt < 2; ++mt) {
            const f16_t* ar = ctxf + (size_t)(mBase + mt*16 + l15) * DIM + k0 + g4*8;
            ah[mt][0] = *(const f16x8*)ar;
            ah[mt][1] = *(const f16x8*)(ar + 32);
        }
        #pragma unroll
        for (int nt = 0; nt < 4; ++nt) {
            const f16_t* wr = wot + (size_t)(nBase + nt*16 + l15) * DIM + k0 + g4*8;
            #pragma unroll
            for (int kk = 0; kk < 2; ++kk) {
                f16x8 bw = *(const f16x8*)(wr + kk*32);
                #pragma unroll
                for (int mt = 0; mt < 2; ++mt)
                    acc[mt][nt] = MFMA16(ah[mt][kk], bw, acc[mt][nt]);
            }
        }
    }
    #pragma unroll
    for (int mt = 0; mt < 2; ++mt) {
        #pragma unroll
        for (int nt = 0; nt < 4; ++nt) {
            const int n = nBase + nt*16 + l15;
            const float bn = bo[n];
            #pragma unroll
            for (int r = 0; r < 4; ++r) {
                const int m = mBase + mt*16 + g4*4 + r;
                out[(size_t)m * DIM + n] = acc[mt][nt][r] + bn;
            }
        }
    }
}

// ---------------------------------------------------------------------------
extern "C" void kernel_launch(void* const* d_in, const int* in_sizes, int n_in,
                              void* d_out, int out_size, void* d_ws, size_t ws_size,
                              hipStream_t stream)
{
    const float* X    = (const float*)d_in[0];
    const float* mask = (const float*)d_in[1];
    const float* Wq   = (const float*)d_in[2];
    const float* bq   = (const float*)d_in[3];
    const float* Wk   = (const float*)d_in[4];
    const float* bk   = (const float*)d_in[5];
    const float* Wv   = (const float*)d_in[6];
    const float* bv   = (const float*)d_in[7];
    const float* Wo   = (const float*)d_in[8];
    const float* bo   = (const float*)d_in[9];

    float* out  = (float*)d_out;                          // [B,S,DIM]
    float* attn = out + (size_t)NB * SEQ * DIM;           // [B,H,S,S]

    const size_t N = (size_t)NB * NH * SEQ * DEPTH;       // 2,097,152
    f16_t* q_h  = (f16_t*)d_ws;
    f16_t* k_h  = q_h + N;
    f16_t* v_t  = k_h + N;
    f16_t* wt   = v_t + N;                                // [1536][512]
    f16_t* wot  = wt + (size_t)3 * DIM * DIM;             // [512][512]
    f16_t* ctxf = wot + (size_t)DIM * DIM;                // [B*S][DIM]
    f16_t* xh   = ctxf + N;                               // [B*S][DIM] fp16 X

    prep_kernel<<<1280, 256, 0, stream>>>(X, Wq, Wk, Wv, Wo, wt, wot, xh);

    qkv_gemm_kernel<<<384, 256, 0, stream>>>(xh, wt, bq, bk, bv, q_h, k_h, v_t);

    attn_kernel<<<512, 256, 0, stream>>>(q_h, k_h, v_t, mask, attn, ctxf);

    out_gemm_kernel<<<256, 256, 0, stream>>>(ctxf, wot, bo, out);
}

// Round 13
// 153.526 us; speedup vs baseline: 1.1643x; 1.1643x over previous
//
#include <hip/hip_runtime.h>
#include <cmath>

#define NB 2
#define SEQ 2048
#define DIM 512
#define NH 8
#define DEPTH 64
#define NT (SEQ / 64)

typedef _Float16 f16_t;
typedef _Float16 f16x4 __attribute__((ext_vector_type(4)));
typedef _Float16 f16x8 __attribute__((ext_vector_type(8)));
typedef float f32x4 __attribute__((ext_vector_type(4)));

#define MFMA16(a, b, c) __builtin_amdgcn_mfma_f32_16x16x32_f16((a), (b), (c), 0, 0, 0)

// ---------------------------------------------------------------------------
// Kernel 1: prep — W^T as fp16 (bx<256) + X -> fp16 (bx>=256). grid 1280.
// ---------------------------------------------------------------------------
__global__ __launch_bounds__(256) void prep_kernel(
    const float* __restrict__ X,
    const float* __restrict__ Wq, const float* __restrict__ Wk,
    const float* __restrict__ Wv, const float* __restrict__ Wo,
    f16_t* __restrict__ wt, f16_t* __restrict__ wot, f16_t* __restrict__ xh)
{
    const int bx = blockIdx.x;
    if (bx >= 256) {
        const size_t i = ((size_t)(bx - 256) * 256 + threadIdx.x) * 8;
        const f32x4 a = *(const f32x4*)(X + i);
        const f32x4 b = *(const f32x4*)(X + i + 4);
        f16x8 o;
        #pragma unroll
        for (int j = 0; j < 4; ++j) { o[j] = (f16_t)a[j]; o[j+4] = (f16_t)b[j]; }
        *(f16x8*)(xh + i) = o;
        return;
    }
    __shared__ float Ws[64][68];
    const int z  = bx >> 6;
    const int kt = (bx >> 3) & 7;
    const int nt = bx & 7;
    const float* W = (z == 0) ? Wq : (z == 1) ? Wk : (z == 2) ? Wv : Wo;
    const int k0 = kt * 64, n0 = nt * 64;
    const int t = threadIdx.x;
    {
        const int r = t >> 2, c0 = (t & 3) * 16;
        #pragma unroll
        for (int j = 0; j < 4; ++j)
            *(f32x4*)&Ws[r][c0 + j*4] =
                *(const f32x4*)&W[(size_t)(k0 + r) * DIM + n0 + c0 + j*4];
    }
    __syncthreads();
    const int n = t >> 2, kc = (t & 3) * 16;
    f16x8 b0, b1;
    #pragma unroll
    for (int j = 0; j < 8; ++j) {
        b0[j] = (f16_t)Ws[kc + j][n];
        b1[j] = (f16_t)Ws[kc + 8 + j][n];
    }
    f16_t* dst = (z < 3) ? (wt + ((size_t)(z * DIM + n0 + n)) * DIM + k0 + kc)
                         : (wot + (size_t)(n0 + n) * DIM + k0 + kc);
    *(f16x8*)dst = b0;
    *(f16x8*)(dst + 8) = b1;
}

// ---------------------------------------------------------------------------
// Kernel 2: QKV projection, direct-global MFMA GEMM on fp16 X.
// Retiled for occupancy: 128x64 block tile, grid 768 (32 mb x 24 nb)
// = 3 blocks/CU (was 384 = 1.5/CU).  Wave tile 64x32 (acc[4][2]).
// ---------------------------------------------------------------------------
__global__ __launch_bounds__(256, 2) void qkv_gemm_kernel(
    const f16_t* __restrict__ xh, const f16_t* __restrict__ wt,
    const float* __restrict__ bq, const float* __restrict__ bk,
    const float* __restrict__ bv,
    f16_t* __restrict__ q_h, f16_t* __restrict__ k_h, f16_t* __restrict__ v_t)
{
    const int bx = blockIdx.x;
    const int mb = bx & 31, nb = bx >> 5;          // 32 mb x 24 nb
    const int tid = threadIdx.x;
    const int w = tid >> 6, lane = tid & 63, l15 = lane & 15, g4 = lane >> 4;
    const int mBase = mb * 128 + (w >> 1) * 64;
    const int nBase = nb * 64 + (w & 1) * 32;

    f32x4 acc[4][2];
    #pragma unroll
    for (int i = 0; i < 4; ++i)
        #pragma unroll
        for (int j = 0; j < 2; ++j) acc[i][j] = (f32x4){0.f, 0.f, 0.f, 0.f};

    for (int k0 = 0; k0 < DIM; k0 += 64) {
        f16x8 ah[4][2];
        #pragma unroll
        for (int mt = 0; mt < 4; ++mt) {
            const f16_t* xr = xh + (size_t)(mBase + mt*16 + l15) * DIM + k0 + g4*8;
            ah[mt][0] = *(const f16x8*)xr;
            ah[mt][1] = *(const f16x8*)(xr + 32);
        }
        #pragma unroll
        for (int nt = 0; nt < 2; ++nt) {
            const f16_t* wr = wt + (size_t)(nBase + nt*16 + l15) * DIM + k0 + g4*8;
            #pragma unroll
            for (int kk = 0; kk < 2; ++kk) {
                f16x8 bw = *(const f16x8*)(wr + kk*32);
                #pragma unroll
                for (int mt = 0; mt < 4; ++mt)
                    acc[mt][nt] = MFMA16(ah[mt][kk], bw, acc[mt][nt]);
            }
        }
    }

    const int z = nb >> 3;                          // 8 nb-blocks per matrix
    const float* bias = (z == 0) ? bq : (z == 1) ? bk : bv;
    #pragma unroll
    for (int mt = 0; mt < 4; ++mt) {
        #pragma unroll
        for (int nt = 0; nt < 2; ++nt) {
            const int n = nBase + nt*16 + l15;      // 0..1535
            const int col = n & 511;
            const int h = (n >> 6) & 7, d = n & 63;
            const float bb = bias[col];
            #pragma unroll
            for (int r = 0; r < 4; ++r) {
                const int m = mBase + mt*16 + g4*4 + r;
                const int b = m >> 11, s = m & (SEQ - 1);
                const int bh = b * NH + h;
                const float v = acc[mt][nt][r] + bb;
                if (z == 2) {
                    v_t[((size_t)bh * DEPTH + d) * SEQ + s] = (f16_t)v;
                } else {
                    const size_t o = ((size_t)bh * SEQ + s) * DEPTH + d;
                    if (z == 0) q_h[o] = (f16_t)v;
                    else        k_h[o] = (f16_t)v;
                }
            }
        }
    }
}

// ---------------------------------------------------------------------------
// Kernel 3: fused two-pass flash attention — r10 champion, byte-identical.
//  - no-max softmax; K/V/mask LDS double-buffered; __syncthreads per tile
//  - swapped-operand QK^T: mfma(K, Q) -> lane q = l15, keys = nt*16+g4*4+r
//  - attn written via p_all readback, full-line mapping (16 lanes = 256B)
// grid 512 = 16 bh x 32 qt (XCD-swizzled), block 256 = 4 waves x 16 q-rows.
// ---------------------------------------------------------------------------
__global__ __launch_bounds__(256, 2) void attn_kernel(
    const f16_t* __restrict__ q_h, const f16_t* __restrict__ k_h,
    const f16_t* __restrict__ v_t, const float* __restrict__ mask,
    float* __restrict__ attn, f16_t* __restrict__ ctxf)
{
    __shared__ __align__(16) unsigned char smem[54784];
    f16_t (*Kh)[64][72] = (f16_t(*)[64][72])smem;            // 2 x 9216 B
    f16_t (*Vt)[64][72] = (f16_t(*)[64][72])(smem + 18432);  // 2 x 9216 B
    float (*p_all)[68]  = (float(*)[68])(smem + 36864);      // [64][68] f32
    float (*mask_s)[64] = (float(*)[64])(smem + 54272);      // 2 x 64 f32
    float (*cx)[68]     = (float(*)[68])smem;                // epilogue overlay

    const int tid = threadIdx.x;
    const int w = tid >> 6, lane = tid & 63;
    const int l15 = lane & 15, g4 = lane >> 4;
    const int rr = tid >> 2;              // staging row (key or d), 0..63
    const int cc = (tid & 3) << 4;        // staging col in f16, 0/16/32/48

    const int id  = blockIdx.x;
    const int nid = (id & 7) * 64 + (id >> 3);            // XCD-contiguous
    const int bh = nid >> 5, qt = nid & 31;
    const int b = bh >> 3, h = bh & 7;

    const size_t kvb = (size_t)bh * SEQ * DEPTH;
    const f16_t* khp = k_h + kvb;
    const f16_t* vtp = v_t + kvb;                         // [64][SEQ]
    const float* mp  = mask + b * SEQ;
    float* attn_p = attn + (size_t)bh * SEQ * SEQ;

    const int qb = qt * 64;
    const int qw = qb + w * 16;

    // Q fragment (B-operand: lane l15 = q row, g4*8 = d chunk)
    f16x8 qf0, qf1;
    {
        const f16_t* qr = q_h + kvb + (size_t)(qw + l15) * DEPTH + g4 * 8;
        qf0 = *(const f16x8*)qr;
        qf1 = *(const f16x8*)(qr + 32);
    }

    float l_r = 0.f;

    // ================= pass 0: sum(exp) (K + mask staged) =================
    {
        const f16_t* s0 = khp + (size_t)rr * DEPTH + cc;
        *(uint4*)&Kh[0][rr][cc]     = *(const uint4*)s0;
        *(uint4*)&Kh[0][rr][cc + 8] = *(const uint4*)(s0 + 8);
        if (tid < 64) mask_s[0][tid] = mp[tid];
    }
    __syncthreads();

    int cur = 0;
    for (int kt = 0; kt < NT; ++kt) {
        const bool have = (kt + 1) < NT;
        uint4 nk0, nk1; float nm = 0.f;
        if (have) {
            const f16_t* src = khp + (size_t)((kt+1)*64 + rr) * DEPTH + cc;
            nk0 = *(const uint4*)src;
            nk1 = *(const uint4*)(src + 8);
            if (tid < 64) nm = mp[(kt+1)*64 + tid];
        }

        #pragma unroll
        for (int nt = 0; nt < 4; ++nt) {
            const f16x8 a0 = *(const f16x8*)&Kh[cur][nt*16 + l15][g4*8];
            const f16x8 a1 = *(const f16x8*)&Kh[cur][nt*16 + l15][32 + g4*8];
            const f32x4 mb = *(const f32x4*)&mask_s[cur][nt*16 + g4*4];
            __builtin_amdgcn_s_setprio(1);
            f32x4 c = {0.f, 0.f, 0.f, 0.f};
            c = MFMA16(a0, qf0, c);
            c = MFMA16(a1, qf1, c);
            __builtin_amdgcn_s_setprio(0);
            #pragma unroll
            for (int r = 0; r < 4; ++r)
                l_r += __expf(c[r] * 0.125f + mb[r] * (-1e9f));
        }

        if (have) {
            *(uint4*)&Kh[cur ^ 1][rr][cc]     = nk0;
            *(uint4*)&Kh[cur ^ 1][rr][cc + 8] = nk1;
            if (tid < 64) mask_s[cur ^ 1][tid] = nm;
        }
        __syncthreads();
        cur ^= 1;
    }
    // deferred cross-lane reduce (sum is linear; no max tracking)
    l_r += __shfl_xor(l_r, 16);
    l_r += __shfl_xor(l_r, 32);
    const float invl = 1.0f / l_r;

    f32x4 cacc[4];
    #pragma unroll
    for (int nt = 0; nt < 4; ++nt) cacc[nt] = (f32x4){0.f, 0.f, 0.f, 0.f};

    // ================= pass 1: recompute, write attn, PV =================
    {
        const f16_t* s0 = khp + (size_t)rr * DEPTH + cc;
        *(uint4*)&Kh[0][rr][cc]     = *(const uint4*)s0;
        *(uint4*)&Kh[0][rr][cc + 8] = *(const uint4*)(s0 + 8);
        const f16_t* s1 = vtp + (size_t)rr * SEQ + cc;
        *(uint4*)&Vt[0][rr][cc]     = *(const uint4*)s1;
        *(uint4*)&Vt[0][rr][cc + 8] = *(const uint4*)(s1 + 8);
        if (tid < 64) mask_s[0][tid] = mp[tid];
    }
    __syncthreads();

    cur = 0;
    for (int kt = 0; kt < NT; ++kt) {
        const int kbase = kt * 64;
        const bool have = (kt + 1) < NT;
        uint4 nk0, nk1, nv0, nv1; float nm = 0.f;
        if (have) {
            const f16_t* srck = khp + (size_t)(kbase + 64 + rr) * DEPTH + cc;
            nk0 = *(const uint4*)srck;
            nk1 = *(const uint4*)(srck + 8);
            const f16_t* srcv = vtp + (size_t)rr * SEQ + kbase + 64 + cc;
            nv0 = *(const uint4*)srcv;
            nv1 = *(const uint4*)(srcv + 8);
            if (tid < 64) nm = mp[kbase + 64 + tid];
        }

        // ---- QK^T + p = exp(s)*invl -> p_all ----
        #pragma unroll
        for (int nt = 0; nt < 4; ++nt) {
            const f16x8 a0 = *(const f16x8*)&Kh[cur][nt*16 + l15][g4*8];
            const f16x8 a1 = *(const f16x8*)&Kh[cur][nt*16 + l15][32 + g4*8];
            const f32x4 mb = *(const f32x4*)&mask_s[cur][nt*16 + g4*4];
            __builtin_amdgcn_s_setprio(1);
            f32x4 c = {0.f, 0.f, 0.f, 0.f};
            c = MFMA16(a0, qf0, c);
            c = MFMA16(a1, qf1, c);
            __builtin_amdgcn_s_setprio(0);
            f32x4 pv;
            #pragma unroll
            for (int r = 0; r < 4; ++r)
                pv[r] = __expf(c[r] * 0.125f + mb[r] * (-1e9f)) * invl;
            *(f32x4*)&p_all[w*16 + l15][nt*16 + g4*4] = pv;
        }
        asm volatile("s_waitcnt lgkmcnt(0)" ::: "memory");
        __builtin_amdgcn_sched_barrier(0);

        // ---- PV: ctx^T[d][q] += V^T[d][k] P^T[k][q] ----
        #pragma unroll
        for (int kk = 0; kk < 2; ++kk) {
            const float* pr = &p_all[w*16 + l15][kk*32 + g4*8];
            const f32x4 p0 = *(const f32x4*)pr;
            const f32x4 p1 = *(const f32x4*)(pr + 4);
            f16x8 pf;
            #pragma unroll
            for (int j = 0; j < 4; ++j) { pf[j] = (f16_t)p0[j]; pf[j+4] = (f16_t)p1[j]; }
            __builtin_amdgcn_s_setprio(1);
            #pragma unroll
            for (int nt = 0; nt < 4; ++nt) {
                const f16x8 vf = *(const f16x8*)&Vt[cur][nt*16 + l15][kk*32 + g4*8];
                cacc[nt] = MFMA16(vf, pf, cacc[nt]);
            }
            __builtin_amdgcn_s_setprio(0);
        }

        // ---- attn store: full-line coalesced (16 lanes = 256B contiguous) ----
        #pragma unroll
        for (int j = 0; j < 4; ++j) {
            const int qloc = j*4 + g4;
            const f32x4 pv = *(const f32x4*)&p_all[w*16 + qloc][l15*4];
            __builtin_nontemporal_store(
                pv, (f32x4*)(attn_p + (size_t)(qw + qloc) * SEQ + kbase + l15*4));
        }

        if (have) {
            *(uint4*)&Kh[cur ^ 1][rr][cc]     = nk0;
            *(uint4*)&Kh[cur ^ 1][rr][cc + 8] = nk1;
            *(uint4*)&Vt[cur ^ 1][rr][cc]     = nv0;
            *(uint4*)&Vt[cur ^ 1][rr][cc + 8] = nv1;
            if (tid < 64) mask_s[cur ^ 1][tid] = nm;
        }
        __syncthreads();
        cur ^= 1;
    }

    // ---- epilogue: transpose ctx^T -> ctx via LDS ----
    #pragma unroll
    for (int nt = 0; nt < 4; ++nt)
        #pragma unroll
        for (int r = 0; r < 4; ++r)
            cx[nt*16 + g4*4 + r][w*16 + l15] = cacc[nt][r];
    __syncthreads();
    {
        const int q = tid >> 2, dc = (tid & 3) << 4;
        f16x8 o0, o1;
        #pragma unroll
        for (int j = 0; j < 8; ++j) {
            o0[j] = (f16_t)cx[dc + j][q];
            o1[j] = (f16_t)cx[dc + 8 + j][q];
        }
        f16_t* dst = ctxf + ((size_t)(b * SEQ) + qb + q) * DIM + h * 64 + dc;
        *(f16x8*)dst = o0;
        *(f16x8*)(dst + 8) = o1;
    }
}

// ---------------------------------------------------------------------------
// Kernel 4: out = ctx @ Wo + bo, direct-global MFMA (fp16).
// grid 256 (64 mb x 4 nb), block 256 (4 waves 2x2, 32x64 per wave)
// ---------------------------------------------------------------------------
__global__ __launch_bounds__(256, 2) void out_gemm_kernel(
    const f16_t* __restrict__ ctxf, const f16_t* __restrict__ wot,
    const float* __restrict__ bo, float* __restrict__ out)
{
    const int bx = blockIdx.x;
    const int mb = bx & 63, nb = bx >> 6;
    const int tid = threadIdx.x;
    const int w = tid >> 6, lane = tid & 63, l15 = lane & 15, g4 = lane >> 4;
    const int mBase = mb * 64 + (w >> 1) * 32;
    const int nBase = nb * 128 + (w & 1) * 64;

    f32x4 acc[2][4];
    #pragma unroll
    for (int i = 0; i < 2; ++i)
        #pragma unroll
        for (int j = 0; j < 4; ++j) acc[i][j] = (f32x4){0.f, 0.f, 0.f, 0.f};

    for (int k0 = 0; k0 < DIM; k0 += 64) {
        f16x8 ah[2][2];
        #pragma unroll
        for (int mt = 0; mt < 2; ++mt) {
            const f16_t* ar = ctxf + (size_t)(mBase + mt*16 + l15) * DIM + k0 + g4*8;
            ah[mt][0] = *(const f16x8*)ar;
            ah[mt][1] = *(const f16x8*)(ar + 32);
        }
        #pragma unroll
        for (int nt = 0; nt < 4; ++nt) {
            const f16_t* wr = wot + (size_t)(nBase + nt*16 + l15) * DIM + k0 + g4*8;
            #pragma unroll
            for (int kk = 0; kk < 2; ++kk) {
                f16x8 bw = *(const f16x8*)(wr + kk*32);
                #pragma unroll
                for (int mt = 0; mt < 2; ++mt)
                    acc[mt][nt] = MFMA16(ah[mt][kk], bw, acc[mt][nt]);
            }
        }
    }
    #pragma unroll
    for (int mt = 0; mt < 2; ++mt) {
        #pragma unroll
        for (int nt = 0; nt < 4; ++nt) {
            const int n = nBase + nt*16 + l15;
            const float bn = bo[n];
            #pragma unroll
            for (int r = 0; r < 4; ++r) {
                const int m = mBase + mt*16 + g4*4 + r;
                out[(size_t)m * DIM + n] = acc[mt][nt][r] + bn;
            }
        }
    }
}

// ---------------------------------------------------------------------------
extern "C" void kernel_launch(void* const* d_in, const int* in_sizes, int n_in,
                              void* d_out, int out_size, void* d_ws, size_t ws_size,
                              hipStream_t stream)
{
    const float* X    = (const float*)d_in[0];
    const float* mask = (const float*)d_in[1];
    const float* Wq   = (const float*)d_in[2];
    const float* bq   = (const float*)d_in[3];
    const float* Wk   = (const float*)d_in[4];
    const float* bk   = (const float*)d_in[5];
    const float* Wv   = (const float*)d_in[6];
    const float* bv   = (const float*)d_in[7];
    const float* Wo   = (const float*)d_in[8];
    const float* bo   = (const float*)d_in[9];

    float* out  = (float*)d_out;                          // [B,S,DIM]
    float* attn = out + (size_t)NB * SEQ * DIM;           // [B,H,S,S]

    const size_t N = (size_t)NB * NH * SEQ * DEPTH;       // 2,097,152
    f16_t* q_h  = (f16_t*)d_ws;
    f16_t* k_h  = q_h + N;
    f16_t* v_t  = k_h + N;
    f16_t* wt   = v_t + N;                                // [1536][512]
    f16_t* wot  = wt + (size_t)3 * DIM * DIM;             // [512][512]
    f16_t* ctxf = wot + (size_t)DIM * DIM;                // [B*S][DIM]
    f16_t* xh   = ctxf + N;                               // [B*S][DIM] fp16 X

    prep_kernel<<<1280, 256, 0, stream>>>(X, Wq, Wk, Wv, Wo, wt, wot, xh);

    qkv_gemm_kernel<<<768, 256, 0, stream>>>(xh, wt, bq, bk, bv, q_h, k_h, v_t);

    attn_kernel<<<512, 256, 0, stream>>>(q_h, k_h, v_t, mask, attn, ctxf);

    out_gemm_kernel<<<256, 256, 0, stream>>>(ctxf, wot, bo, out);
}

// Round 14
// 152.839 us; speedup vs baseline: 1.1695x; 1.0045x over previous
//
#include <hip/hip_runtime.h>
#include <cmath>

#define NB 2
#define SEQ 2048
#define DIM 512
#define NH 8
#define DEPTH 64
#define NT (SEQ / 64)

typedef _Float16 f16_t;
typedef _Float16 f16x4 __attribute__((ext_vector_type(4)));
typedef _Float16 f16x8 __attribute__((ext_vector_type(8)));
typedef float f32x4 __attribute__((ext_vector_type(4)));

#define MFMA16(a, b, c) __builtin_amdgcn_mfma_f32_16x16x32_f16((a), (b), (c), 0, 0, 0)

// LDS-visibility barrier: waits LDS ops only, never drains vmcnt — in-flight
// nontemporal stores keep retiring across the barrier. Sole cross-wave state
// in attn_kernel is LDS, so this is semantically sufficient.
#define LDS_SYNC() asm volatile("s_waitcnt lgkmcnt(0)\n\ts_barrier" ::: "memory")

// ---------------------------------------------------------------------------
// Kernel 1: prep — W^T as fp16 (bx<256) + X -> fp16 (bx>=256). grid 1280.
// ---------------------------------------------------------------------------
__global__ __launch_bounds__(256) void prep_kernel(
    const float* __restrict__ X,
    const float* __restrict__ Wq, const float* __restrict__ Wk,
    const float* __restrict__ Wv, const float* __restrict__ Wo,
    f16_t* __restrict__ wt, f16_t* __restrict__ wot, f16_t* __restrict__ xh)
{
    const int bx = blockIdx.x;
    if (bx >= 256) {
        const size_t i = ((size_t)(bx - 256) * 256 + threadIdx.x) * 8;
        const f32x4 a = *(const f32x4*)(X + i);
        const f32x4 b = *(const f32x4*)(X + i + 4);
        f16x8 o;
        #pragma unroll
        for (int j = 0; j < 4; ++j) { o[j] = (f16_t)a[j]; o[j+4] = (f16_t)b[j]; }
        *(f16x8*)(xh + i) = o;
        return;
    }
    __shared__ float Ws[64][68];
    const int z  = bx >> 6;
    const int kt = (bx >> 3) & 7;
    const int nt = bx & 7;
    const float* W = (z == 0) ? Wq : (z == 1) ? Wk : (z == 2) ? Wv : Wo;
    const int k0 = kt * 64, n0 = nt * 64;
    const int t = threadIdx.x;
    {
        const int r = t >> 2, c0 = (t & 3) * 16;
        #pragma unroll
        for (int j = 0; j < 4; ++j)
            *(f32x4*)&Ws[r][c0 + j*4] =
                *(const f32x4*)&W[(size_t)(k0 + r) * DIM + n0 + c0 + j*4];
    }
    __syncthreads();
    const int n = t >> 2, kc = (t & 3) * 16;
    f16x8 b0, b1;
    #pragma unroll
    for (int j = 0; j < 8; ++j) {
        b0[j] = (f16_t)Ws[kc + j][n];
        b1[j] = (f16_t)Ws[kc + 8 + j][n];
    }
    f16_t* dst = (z < 3) ? (wt + ((size_t)(z * DIM + n0 + n)) * DIM + k0 + kc)
                         : (wot + (size_t)(n0 + n) * DIM + k0 + kc);
    *(f16x8*)dst = b0;
    *(f16x8*)(dst + 8) = b1;
}

// ---------------------------------------------------------------------------
// Kernel 2: QKV projection, direct-global MFMA GEMM on fp16 X.
// 128x64 block tile, grid 768 (32 mb x 24 nb) = 3 blocks/CU.
// ---------------------------------------------------------------------------
__global__ __launch_bounds__(256, 2) void qkv_gemm_kernel(
    const f16_t* __restrict__ xh, const f16_t* __restrict__ wt,
    const float* __restrict__ bq, const float* __restrict__ bk,
    const float* __restrict__ bv,
    f16_t* __restrict__ q_h, f16_t* __restrict__ k_h, f16_t* __restrict__ v_t)
{
    const int bx = blockIdx.x;
    const int mb = bx & 31, nb = bx >> 5;          // 32 mb x 24 nb
    const int tid = threadIdx.x;
    const int w = tid >> 6, lane = tid & 63, l15 = lane & 15, g4 = lane >> 4;
    const int mBase = mb * 128 + (w >> 1) * 64;
    const int nBase = nb * 64 + (w & 1) * 32;

    f32x4 acc[4][2];
    #pragma unroll
    for (int i = 0; i < 4; ++i)
        #pragma unroll
        for (int j = 0; j < 2; ++j) acc[i][j] = (f32x4){0.f, 0.f, 0.f, 0.f};

    for (int k0 = 0; k0 < DIM; k0 += 64) {
        f16x8 ah[4][2];
        #pragma unroll
        for (int mt = 0; mt < 4; ++mt) {
            const f16_t* xr = xh + (size_t)(mBase + mt*16 + l15) * DIM + k0 + g4*8;
            ah[mt][0] = *(const f16x8*)xr;
            ah[mt][1] = *(const f16x8*)(xr + 32);
        }
        #pragma unroll
        for (int nt = 0; nt < 2; ++nt) {
            const f16_t* wr = wt + (size_t)(nBase + nt*16 + l15) * DIM + k0 + g4*8;
            #pragma unroll
            for (int kk = 0; kk < 2; ++kk) {
                f16x8 bw = *(const f16x8*)(wr + kk*32);
                #pragma unroll
                for (int mt = 0; mt < 4; ++mt)
                    acc[mt][nt] = MFMA16(ah[mt][kk], bw, acc[mt][nt]);
            }
        }
    }

    const int z = nb >> 3;                          // 8 nb-blocks per matrix
    const float* bias = (z == 0) ? bq : (z == 1) ? bk : bv;
    #pragma unroll
    for (int mt = 0; mt < 4; ++mt) {
        #pragma unroll
        for (int nt = 0; nt < 2; ++nt) {
            const int n = nBase + nt*16 + l15;      // 0..1535
            const int col = n & 511;
            const int h = (n >> 6) & 7, d = n & 63;
            const float bb = bias[col];
            #pragma unroll
            for (int r = 0; r < 4; ++r) {
                const int m = mBase + mt*16 + g4*4 + r;
                const int b = m >> 11, s = m & (SEQ - 1);
                const int bh = b * NH + h;
                const float v = acc[mt][nt][r] + bb;
                if (z == 2) {
                    v_t[((size_t)bh * DEPTH + d) * SEQ + s] = (f16_t)v;
                } else {
                    const size_t o = ((size_t)bh * SEQ + s) * DEPTH + d;
                    if (z == 0) q_h[o] = (f16_t)v;
                    else        k_h[o] = (f16_t)v;
                }
            }
        }
    }
}

// ---------------------------------------------------------------------------
// Kernel 3: fused two-pass flash attention — r13 champion, ONE change:
// all __syncthreads() -> LDS_SYNC() (lgkm-only barrier; NT attn stores are
// never drained per-tile, only at endpgm).
//  - no-max softmax; K/V/mask LDS double-buffered
//  - swapped-operand QK^T: mfma(K, Q) -> lane q = l15, keys = nt*16+g4*4+r
//  - attn written via p_all readback, full-line mapping (16 lanes = 256B)
// grid 512 = 16 bh x 32 qt (XCD-swizzled), block 256 = 4 waves x 16 q-rows.
// ---------------------------------------------------------------------------
__global__ __launch_bounds__(256, 2) void attn_kernel(
    const f16_t* __restrict__ q_h, const f16_t* __restrict__ k_h,
    const f16_t* __restrict__ v_t, const float* __restrict__ mask,
    float* __restrict__ attn, f16_t* __restrict__ ctxf)
{
    __shared__ __align__(16) unsigned char smem[54784];
    f16_t (*Kh)[64][72] = (f16_t(*)[64][72])smem;            // 2 x 9216 B
    f16_t (*Vt)[64][72] = (f16_t(*)[64][72])(smem + 18432);  // 2 x 9216 B
    float (*p_all)[68]  = (float(*)[68])(smem + 36864);      // [64][68] f32
    float (*mask_s)[64] = (float(*)[64])(smem + 54272);      // 2 x 64 f32
    float (*cx)[68]     = (float(*)[68])smem;                // epilogue overlay

    const int tid = threadIdx.x;
    const int w = tid >> 6, lane = tid & 63;
    const int l15 = lane & 15, g4 = lane >> 4;
    const int rr = tid >> 2;              // staging row (key or d), 0..63
    const int cc = (tid & 3) << 4;        // staging col in f16, 0/16/32/48

    const int id  = blockIdx.x;
    const int nid = (id & 7) * 64 + (id >> 3);            // XCD-contiguous
    const int bh = nid >> 5, qt = nid & 31;
    const int b = bh >> 3, h = bh & 7;

    const size_t kvb = (size_t)bh * SEQ * DEPTH;
    const f16_t* khp = k_h + kvb;
    const f16_t* vtp = v_t + kvb;                         // [64][SEQ]
    const float* mp  = mask + b * SEQ;
    float* attn_p = attn + (size_t)bh * SEQ * SEQ;

    const int qb = qt * 64;
    const int qw = qb + w * 16;

    // Q fragment (B-operand: lane l15 = q row, g4*8 = d chunk)
    f16x8 qf0, qf1;
    {
        const f16_t* qr = q_h + kvb + (size_t)(qw + l15) * DEPTH + g4 * 8;
        qf0 = *(const f16x8*)qr;
        qf1 = *(const f16x8*)(qr + 32);
    }

    float l_r = 0.f;

    // ================= pass 0: sum(exp) (K + mask staged) =================
    {
        const f16_t* s0 = khp + (size_t)rr * DEPTH + cc;
        *(uint4*)&Kh[0][rr][cc]     = *(const uint4*)s0;
        *(uint4*)&Kh[0][rr][cc + 8] = *(const uint4*)(s0 + 8);
        if (tid < 64) mask_s[0][tid] = mp[tid];
    }
    LDS_SYNC();

    int cur = 0;
    for (int kt = 0; kt < NT; ++kt) {
        const bool have = (kt + 1) < NT;
        uint4 nk0, nk1; float nm = 0.f;
        if (have) {
            const f16_t* src = khp + (size_t)((kt+1)*64 + rr) * DEPTH + cc;
            nk0 = *(const uint4*)src;
            nk1 = *(const uint4*)(src + 8);
            if (tid < 64) nm = mp[(kt+1)*64 + tid];
        }

        #pragma unroll
        for (int nt = 0; nt < 4; ++nt) {
            const f16x8 a0 = *(const f16x8*)&Kh[cur][nt*16 + l15][g4*8];
            const f16x8 a1 = *(const f16x8*)&Kh[cur][nt*16 + l15][32 + g4*8];
            const f32x4 mb = *(const f32x4*)&mask_s[cur][nt*16 + g4*4];
            __builtin_amdgcn_s_setprio(1);
            f32x4 c = {0.f, 0.f, 0.f, 0.f};
            c = MFMA16(a0, qf0, c);
            c = MFMA16(a1, qf1, c);
            __builtin_amdgcn_s_setprio(0);
            #pragma unroll
            for (int r = 0; r < 4; ++r)
                l_r += __expf(c[r] * 0.125f + mb[r] * (-1e9f));
        }

        if (have) {
            *(uint4*)&Kh[cur ^ 1][rr][cc]     = nk0;
            *(uint4*)&Kh[cur ^ 1][rr][cc + 8] = nk1;
            if (tid < 64) mask_s[cur ^ 1][tid] = nm;
        }
        LDS_SYNC();
        cur ^= 1;
    }
    // deferred cross-lane reduce (sum is linear; no max tracking)
    l_r += __shfl_xor(l_r, 16);
    l_r += __shfl_xor(l_r, 32);
    const float invl = 1.0f / l_r;

    f32x4 cacc[4];
    #pragma unroll
    for (int nt = 0; nt < 4; ++nt) cacc[nt] = (f32x4){0.f, 0.f, 0.f, 0.f};

    // ================= pass 1: recompute, write attn, PV =================
    {
        const f16_t* s0 = khp + (size_t)rr * DEPTH + cc;
        *(uint4*)&Kh[0][rr][cc]     = *(const uint4*)s0;
        *(uint4*)&Kh[0][rr][cc + 8] = *(const uint4*)(s0 + 8);
        const f16_t* s1 = vtp + (size_t)rr * SEQ + cc;
        *(uint4*)&Vt[0][rr][cc]     = *(const uint4*)s1;
        *(uint4*)&Vt[0][rr][cc + 8] = *(const uint4*)(s1 + 8);
        if (tid < 64) mask_s[0][tid] = mp[tid];
    }
    LDS_SYNC();

    cur = 0;
    for (int kt = 0; kt < NT; ++kt) {
        const int kbase = kt * 64;
        const bool have = (kt + 1) < NT;
        uint4 nk0, nk1, nv0, nv1; float nm = 0.f;
        if (have) {
            const f16_t* srck = khp + (size_t)(kbase + 64 + rr) * DEPTH + cc;
            nk0 = *(const uint4*)srck;
            nk1 = *(const uint4*)(srck + 8);
            const f16_t* srcv = vtp + (size_t)rr * SEQ + kbase + 64 + cc;
            nv0 = *(const uint4*)srcv;
            nv1 = *(const uint4*)(srcv + 8);
            if (tid < 64) nm = mp[kbase + 64 + tid];
        }

        // ---- QK^T + p = exp(s)*invl -> p_all ----
        #pragma unroll
        for (int nt = 0; nt < 4; ++nt) {
            const f16x8 a0 = *(const f16x8*)&Kh[cur][nt*16 + l15][g4*8];
            const f16x8 a1 = *(const f16x8*)&Kh[cur][nt*16 + l15][32 + g4*8];
            const f32x4 mb = *(const f32x4*)&mask_s[cur][nt*16 + g4*4];
            __builtin_amdgcn_s_setprio(1);
            f32x4 c = {0.f, 0.f, 0.f, 0.f};
            c = MFMA16(a0, qf0, c);
            c = MFMA16(a1, qf1, c);
            __builtin_amdgcn_s_setprio(0);
            f32x4 pv;
            #pragma unroll
            for (int r = 0; r < 4; ++r)
                pv[r] = __expf(c[r] * 0.125f + mb[r] * (-1e9f)) * invl;
            *(f32x4*)&p_all[w*16 + l15][nt*16 + g4*4] = pv;
        }
        asm volatile("s_waitcnt lgkmcnt(0)" ::: "memory");
        __builtin_amdgcn_sched_barrier(0);

        // ---- PV: ctx^T[d][q] += V^T[d][k] P^T[k][q] ----
        #pragma unroll
        for (int kk = 0; kk < 2; ++kk) {
            const float* pr = &p_all[w*16 + l15][kk*32 + g4*8];
            const f32x4 p0 = *(const f32x4*)pr;
            const f32x4 p1 = *(const f32x4*)(pr + 4);
            f16x8 pf;
            #pragma unroll
            for (int j = 0; j < 4; ++j) { pf[j] = (f16_t)p0[j]; pf[j+4] = (f16_t)p1[j]; }
            __builtin_amdgcn_s_setprio(1);
            #pragma unroll
            for (int nt = 0; nt < 4; ++nt) {
                const f16x8 vf = *(const f16x8*)&Vt[cur][nt*16 + l15][kk*32 + g4*8];
                cacc[nt] = MFMA16(vf, pf, cacc[nt]);
            }
            __builtin_amdgcn_s_setprio(0);
        }

        // ---- attn store: full-line coalesced (16 lanes = 256B contiguous) ----
        #pragma unroll
        for (int j = 0; j < 4; ++j) {
            const int qloc = j*4 + g4;
            const f32x4 pv = *(const f32x4*)&p_all[w*16 + qloc][l15*4];
            __builtin_nontemporal_store(
                pv, (f32x4*)(attn_p + (size_t)(qw + qloc) * SEQ + kbase + l15*4));
        }

        if (have) {
            *(uint4*)&Kh[cur ^ 1][rr][cc]     = nk0;
            *(uint4*)&Kh[cur ^ 1][rr][cc + 8] = nk1;
            *(uint4*)&Vt[cur ^ 1][rr][cc]     = nv0;
            *(uint4*)&Vt[cur ^ 1][rr][cc + 8] = nv1;
            if (tid < 64) mask_s[cur ^ 1][tid] = nm;
        }
        LDS_SYNC();
        cur ^= 1;
    }

    // ---- epilogue: transpose ctx^T -> ctx via LDS ----
    #pragma unroll
    for (int nt = 0; nt < 4; ++nt)
        #pragma unroll
        for (int r = 0; r < 4; ++r)
            cx[nt*16 + g4*4 + r][w*16 + l15] = cacc[nt][r];
    LDS_SYNC();
    {
        const int q = tid >> 2, dc = (tid & 3) << 4;
        f16x8 o0, o1;
        #pragma unroll
        for (int j = 0; j < 8; ++j) {
            o0[j] = (f16_t)cx[dc + j][q];
            o1[j] = (f16_t)cx[dc + 8 + j][q];
        }
        f16_t* dst = ctxf + ((size_t)(b * SEQ) + qb + q) * DIM + h * 64 + dc;
        *(f16x8*)dst = o0;
        *(f16x8*)(dst + 8) = o1;
    }
}

// ---------------------------------------------------------------------------
// Kernel 4: out = ctx @ Wo + bo, direct-global MFMA (fp16).
// grid 256 (64 mb x 4 nb), block 256 (4 waves 2x2, 32x64 per wave)
// ---------------------------------------------------------------------------
__global__ __launch_bounds__(256, 2) void out_gemm_kernel(
    const f16_t* __restrict__ ctxf, const f16_t* __restrict__ wot,
    const float* __restrict__ bo, float* __restrict__ out)
{
    const int bx = blockIdx.x;
    const int mb = bx & 63, nb = bx >> 6;
    const int tid = threadIdx.x;
    const int w = tid >> 6, lane = tid & 63, l15 = lane & 15, g4 = lane >> 4;
    const int mBase = mb * 64 + (w >> 1) * 32;
    const int nBase = nb * 128 + (w & 1) * 64;

    f32x4 acc[2][4];
    #pragma unroll
    for (int i = 0; i < 2; ++i)
        #pragma unroll
        for (int j = 0; j < 4; ++j) acc[i][j] = (f32x4){0.f, 0.f, 0.f, 0.f};

    for (int k0 = 0; k0 < DIM; k0 += 64) {
        f16x8 ah[2][2];
        #pragma unroll
        for (int mt = 0; mt < 2; ++mt) {
            const f16_t* ar = ctxf + (size_t)(mBase + mt*16 + l15) * DIM + k0 + g4*8;
            ah[mt][0] = *(const f16x8*)ar;
            ah[mt][1] = *(const f16x8*)(ar + 32);
        }
        #pragma unroll
        for (int nt = 0; nt < 4; ++nt) {
            const f16_t* wr = wot + (size_t)(nBase + nt*16 + l15) * DIM + k0 + g4*8;
            #pragma unroll
            for (int kk = 0; kk < 2; ++kk) {
                f16x8 bw = *(const f16x8*)(wr + kk*32);
                #pragma unroll
                for (int mt = 0; mt < 2; ++mt)
                    acc[mt][nt] = MFMA16(ah[mt][kk], bw, acc[mt][nt]);
            }
        }
    }
    #pragma unroll
    for (int mt = 0; mt < 2; ++mt) {
        #pragma unroll
        for (int nt = 0; nt < 4; ++nt) {
            const int n = nBase + nt*16 + l15;
            const float bn = bo[n];
            #pragma unroll
            for (int r = 0; r < 4; ++r) {
                const int m = mBase + mt*16 + g4*4 + r;
                out[(size_t)m * DIM + n] = acc[mt][nt][r] + bn;
            }
        }
    }
}

// ---------------------------------------------------------------------------
extern "C" void kernel_launch(void* const* d_in, const int* in_sizes, int n_in,
                              void* d_out, int out_size, void* d_ws, size_t ws_size,
                              hipStream_t stream)
{
    const float* X    = (const float*)d_in[0];
    const float* mask = (const float*)d_in[1];
    const float* Wq   = (const float*)d_in[2];
    const float* bq   = (const float*)d_in[3];
    const float* Wk   = (const float*)d_in[4];
    const float* bk   = (const float*)d_in[5];
    const float* Wv   = (const float*)d_in[6];
    const float* bv   = (const float*)d_in[7];
    const float* Wo   = (const float*)d_in[8];
    const float* bo   = (const float*)d_in[9];

    float* out  = (float*)d_out;                          // [B,S,DIM]
    float* attn = out + (size_t)NB * SEQ * DIM;           // [B,H,S,S]

    const size_t N = (size_t)NB * NH * SEQ * DEPTH;       // 2,097,152
    f16_t* q_h  = (f16_t*)d_ws;
    f16_t* k_h  = q_h + N;
    f16_t* v_t  = k_h + N;
    f16_t* wt   = v_t + N;                                // [1536][512]
    f16_t* wot  = wt + (size_t)3 * DIM * DIM;             // [512][512]
    f16_t* ctxf = wot + (size_t)DIM * DIM;                // [B*S][DIM]
    f16_t* xh   = ctxf + N;                               // [B*S][DIM] fp16 X

    prep_kernel<<<1280, 256, 0, stream>>>(X, Wq, Wk, Wv, Wo, wt, wot, xh);

    qkv_gemm_kernel<<<768, 256, 0, stream>>>(xh, wt, bq, bk, bv, q_h, k_h, v_t);

    attn_kernel<<<512, 256, 0, stream>>>(q_h, k_h, v_t, mask, attn, ctxf);

    out_gemm_kernel<<<256, 256, 0, stream>>>(ctxf, wot, bo, out);
}

// Round 15
// 151.337 us; speedup vs baseline: 1.1811x; 1.0099x over previous
//
#include <hip/hip_runtime.h>
#include <cmath>

#define NB 2
#define SEQ 2048
#define DIM 512
#define NH 8
#define DEPTH 64
#define NT (SEQ / 64)

typedef _Float16 f16_t;
typedef _Float16 f16x4 __attribute__((ext_vector_type(4)));
typedef _Float16 f16x8 __attribute__((ext_vector_type(8)));
typedef float f32x4 __attribute__((ext_vector_type(4)));

#define MFMA16(a, b, c) __builtin_amdgcn_mfma_f32_16x16x32_f16((a), (b), (c), 0, 0, 0)

// LDS-visibility barrier: waits LDS ops only, never drains vmcnt.
#define LDS_SYNC() asm volatile("s_waitcnt lgkmcnt(0)\n\ts_barrier" ::: "memory")

// ---------------------------------------------------------------------------
// Kernel 1: prep — W^T as fp16 (bx<256) + X -> fp16 (bx>=256). grid 1280.
// ---------------------------------------------------------------------------
__global__ __launch_bounds__(256) void prep_kernel(
    const float* __restrict__ X,
    const float* __restrict__ Wq, const float* __restrict__ Wk,
    const float* __restrict__ Wv, const float* __restrict__ Wo,
    f16_t* __restrict__ wt, f16_t* __restrict__ wot, f16_t* __restrict__ xh)
{
    const int bx = blockIdx.x;
    if (bx >= 256) {
        const size_t i = ((size_t)(bx - 256) * 256 + threadIdx.x) * 8;
        const f32x4 a = *(const f32x4*)(X + i);
        const f32x4 b = *(const f32x4*)(X + i + 4);
        f16x8 o;
        #pragma unroll
        for (int j = 0; j < 4; ++j) { o[j] = (f16_t)a[j]; o[j+4] = (f16_t)b[j]; }
        *(f16x8*)(xh + i) = o;
        return;
    }
    __shared__ float Ws[64][68];
    const int z  = bx >> 6;
    const int kt = (bx >> 3) & 7;
    const int nt = bx & 7;
    const float* W = (z == 0) ? Wq : (z == 1) ? Wk : (z == 2) ? Wv : Wo;
    const int k0 = kt * 64, n0 = nt * 64;
    const int t = threadIdx.x;
    {
        const int r = t >> 2, c0 = (t & 3) * 16;
        #pragma unroll
        for (int j = 0; j < 4; ++j)
            *(f32x4*)&Ws[r][c0 + j*4] =
                *(const f32x4*)&W[(size_t)(k0 + r) * DIM + n0 + c0 + j*4];
    }
    __syncthreads();
    const int n = t >> 2, kc = (t & 3) * 16;
    f16x8 b0, b1;
    #pragma unroll
    for (int j = 0; j < 8; ++j) {
        b0[j] = (f16_t)Ws[kc + j][n];
        b1[j] = (f16_t)Ws[kc + 8 + j][n];
    }
    f16_t* dst = (z < 3) ? (wt + ((size_t)(z * DIM + n0 + n)) * DIM + k0 + kc)
                         : (wot + (size_t)(n0 + n) * DIM + k0 + kc);
    *(f16x8*)dst = b0;
    *(f16x8*)(dst + 8) = b1;
}

// ---------------------------------------------------------------------------
// Kernel 2: QKV projection, direct-global MFMA GEMM on fp16 X.
// 128x64 block tile, grid 768 (32 mb x 24 nb) = 3 blocks/CU.
// ---------------------------------------------------------------------------
__global__ __launch_bounds__(256, 2) void qkv_gemm_kernel(
    const f16_t* __restrict__ xh, const f16_t* __restrict__ wt,
    const float* __restrict__ bq, const float* __restrict__ bk,
    const float* __restrict__ bv,
    f16_t* __restrict__ q_h, f16_t* __restrict__ k_h, f16_t* __restrict__ v_t)
{
    const int bx = blockIdx.x;
    const int mb = bx & 31, nb = bx >> 5;          // 32 mb x 24 nb
    const int tid = threadIdx.x;
    const int w = tid >> 6, lane = tid & 63, l15 = lane & 15, g4 = lane >> 4;
    const int mBase = mb * 128 + (w >> 1) * 64;
    const int nBase = nb * 64 + (w & 1) * 32;

    f32x4 acc[4][2];
    #pragma unroll
    for (int i = 0; i < 4; ++i)
        #pragma unroll
        for (int j = 0; j < 2; ++j) acc[i][j] = (f32x4){0.f, 0.f, 0.f, 0.f};

    for (int k0 = 0; k0 < DIM; k0 += 64) {
        f16x8 ah[4][2];
        #pragma unroll
        for (int mt = 0; mt < 4; ++mt) {
            const f16_t* xr = xh + (size_t)(mBase + mt*16 + l15) * DIM + k0 + g4*8;
            ah[mt][0] = *(const f16x8*)xr;
            ah[mt][1] = *(const f16x8*)(xr + 32);
        }
        #pragma unroll
        for (int nt = 0; nt < 2; ++nt) {
            const f16_t* wr = wt + (size_t)(nBase + nt*16 + l15) * DIM + k0 + g4*8;
            #pragma unroll
            for (int kk = 0; kk < 2; ++kk) {
                f16x8 bw = *(const f16x8*)(wr + kk*32);
                #pragma unroll
                for (int mt = 0; mt < 4; ++mt)
                    acc[mt][nt] = MFMA16(ah[mt][kk], bw, acc[mt][nt]);
            }
        }
    }

    const int z = nb >> 3;                          // 8 nb-blocks per matrix
    const float* bias = (z == 0) ? bq : (z == 1) ? bk : bv;
    #pragma unroll
    for (int mt = 0; mt < 4; ++mt) {
        #pragma unroll
        for (int nt = 0; nt < 2; ++nt) {
            const int n = nBase + nt*16 + l15;      // 0..1535
            const int col = n & 511;
            const int h = (n >> 6) & 7, d = n & 63;
            const float bb = bias[col];
            #pragma unroll
            for (int r = 0; r < 4; ++r) {
                const int m = mBase + mt*16 + g4*4 + r;
                const int b = m >> 11, s = m & (SEQ - 1);
                const int bh = b * NH + h;
                const float v = acc[mt][nt][r] + bb;
                if (z == 2) {
                    v_t[((size_t)bh * DEPTH + d) * SEQ + s] = (f16_t)v;
                } else {
                    const size_t o = ((size_t)bh * SEQ + s) * DEPTH + d;
                    if (z == 0) q_h[o] = (f16_t)v;
                    else        k_h[o] = (f16_t)v;
                }
            }
        }
    }
}

// ---------------------------------------------------------------------------
// Kernel 3: fused two-pass flash attention — r14 champion, ONE change:
// pass 0 stages K in 128-key double-buffered tiles (overlaid on the K+V
// LDS region; mask overlays p_all space) -> pass-0 barrier count 32 -> 16,
// 2x compute per staging round. Per-lane exp summation order unchanged
// (ascending k) -> bit-identical l_r.
//  - no-max softmax; lgkm-only barriers; pass 1 unchanged from r14
//  - swapped-operand QK^T: mfma(K, Q) -> lane q = l15, keys = nt*16+g4*4+r
//  - attn written via p_all readback, full-line mapping (16 lanes = 256B)
// grid 512 = 16 bh x 32 qt (XCD-swizzled), block 256 = 4 waves x 16 q-rows.
// ---------------------------------------------------------------------------
__global__ __launch_bounds__(256, 2) void attn_kernel(
    const f16_t* __restrict__ q_h, const f16_t* __restrict__ k_h,
    const f16_t* __restrict__ v_t, const float* __restrict__ mask,
    float* __restrict__ attn, f16_t* __restrict__ ctxf)
{
    __shared__ __align__(16) unsigned char smem[54784];
    f16_t (*Kh)[64][72] = (f16_t(*)[64][72])smem;            // 2 x 9216 B
    f16_t (*Vt)[64][72] = (f16_t(*)[64][72])(smem + 18432);  // 2 x 9216 B
    float (*p_all)[68]  = (float(*)[68])(smem + 36864);      // [64][68] f32
    float (*mask_s)[64] = (float(*)[64])(smem + 54272);      // 2 x 64 f32
    float (*cx)[68]     = (float(*)[68])smem;                // epilogue overlay
    // pass-0 overlays (K+V region is free of V in pass 0):
    f16_t (*K2)[128][72] = (f16_t(*)[128][72])smem;          // 2 x 18432 B
    float (*mask2)[128]  = (float(*)[128])(smem + 36864);    // 2 x 512 B

    const int tid = threadIdx.x;
    const int w = tid >> 6, lane = tid & 63;
    const int l15 = lane & 15, g4 = lane >> 4;
    const int rr = tid >> 2;              // 64-row staging: row, 0..63
    const int cc = (tid & 3) << 4;        // 64-row staging: col f16, 0/16/32/48
    const int r2 = tid >> 1;              // 128-row staging: row, 0..127
    const int c2 = (tid & 1) << 5;        // 128-row staging: col f16, 0/32

    const int id  = blockIdx.x;
    const int nid = (id & 7) * 64 + (id >> 3);            // XCD-contiguous
    const int bh = nid >> 5, qt = nid & 31;
    const int b = bh >> 3, h = bh & 7;

    const size_t kvb = (size_t)bh * SEQ * DEPTH;
    const f16_t* khp = k_h + kvb;
    const f16_t* vtp = v_t + kvb;                         // [64][SEQ]
    const float* mp  = mask + b * SEQ;
    float* attn_p = attn + (size_t)bh * SEQ * SEQ;

    const int qb = qt * 64;
    const int qw = qb + w * 16;

    // Q fragment (B-operand: lane l15 = q row, g4*8 = d chunk)
    f16x8 qf0, qf1;
    {
        const f16_t* qr = q_h + kvb + (size_t)(qw + l15) * DEPTH + g4 * 8;
        qf0 = *(const f16x8*)qr;
        qf1 = *(const f16x8*)(qr + 32);
    }

    float l_r = 0.f;

    // ====== pass 0: sum(exp), 128-key double-buffered K tiles ======
    {
        const f16_t* s0 = khp + (size_t)r2 * DEPTH + c2;
        *(uint4*)&K2[0][r2][c2]      = *(const uint4*)s0;
        *(uint4*)&K2[0][r2][c2 + 8]  = *(const uint4*)(s0 + 8);
        *(uint4*)&K2[0][r2][c2 + 16] = *(const uint4*)(s0 + 16);
        *(uint4*)&K2[0][r2][c2 + 24] = *(const uint4*)(s0 + 24);
        if (tid < 128) mask2[0][tid] = mp[tid];
    }
    LDS_SYNC();

    int cur = 0;
    for (int kt = 0; kt < NT / 2; ++kt) {
        const bool have = (kt + 1) < NT / 2;
        uint4 nk[4]; float nm = 0.f;
        if (have) {
            const f16_t* src = khp + (size_t)((kt+1)*128 + r2) * DEPTH + c2;
            nk[0] = *(const uint4*)src;
            nk[1] = *(const uint4*)(src + 8);
            nk[2] = *(const uint4*)(src + 16);
            nk[3] = *(const uint4*)(src + 24);
            if (tid < 128) nm = mp[(kt+1)*128 + tid];
        }

        #pragma unroll
        for (int nt = 0; nt < 8; ++nt) {
            const f16x8 a0 = *(const f16x8*)&K2[cur][nt*16 + l15][g4*8];
            const f16x8 a1 = *(const f16x8*)&K2[cur][nt*16 + l15][32 + g4*8];
            const f32x4 mb = *(const f32x4*)&mask2[cur][nt*16 + g4*4];
            __builtin_amdgcn_s_setprio(1);
            f32x4 c = {0.f, 0.f, 0.f, 0.f};
            c = MFMA16(a0, qf0, c);
            c = MFMA16(a1, qf1, c);
            __builtin_amdgcn_s_setprio(0);
            #pragma unroll
            for (int r = 0; r < 4; ++r)
                l_r += __expf(c[r] * 0.125f + mb[r] * (-1e9f));
        }

        if (have) {
            *(uint4*)&K2[cur ^ 1][r2][c2]      = nk[0];
            *(uint4*)&K2[cur ^ 1][r2][c2 + 8]  = nk[1];
            *(uint4*)&K2[cur ^ 1][r2][c2 + 16] = nk[2];
            *(uint4*)&K2[cur ^ 1][r2][c2 + 24] = nk[3];
            if (tid < 128) mask2[cur ^ 1][tid] = nm;
        }
        LDS_SYNC();
        cur ^= 1;
    }
    // deferred cross-lane reduce (sum is linear; no max tracking)
    l_r += __shfl_xor(l_r, 16);
    l_r += __shfl_xor(l_r, 32);
    const float invl = 1.0f / l_r;

    f32x4 cacc[4];
    #pragma unroll
    for (int nt = 0; nt < 4; ++nt) cacc[nt] = (f32x4){0.f, 0.f, 0.f, 0.f};

    // ================= pass 1: recompute, write attn, PV =================
    {
        const f16_t* s0 = khp + (size_t)rr * DEPTH + cc;
        *(uint4*)&Kh[0][rr][cc]     = *(const uint4*)s0;
        *(uint4*)&Kh[0][rr][cc + 8] = *(const uint4*)(s0 + 8);
        const f16_t* s1 = vtp + (size_t)rr * SEQ + cc;
        *(uint4*)&Vt[0][rr][cc]     = *(const uint4*)s1;
        *(uint4*)&Vt[0][rr][cc + 8] = *(const uint4*)(s1 + 8);
        if (tid < 64) mask_s[0][tid] = mp[tid];
    }
    LDS_SYNC();

    cur = 0;
    for (int kt = 0; kt < NT; ++kt) {
        const int kbase = kt * 64;
        const bool have = (kt + 1) < NT;
        uint4 nk0, nk1, nv0, nv1; float nm = 0.f;
        if (have) {
            const f16_t* srck = khp + (size_t)(kbase + 64 + rr) * DEPTH + cc;
            nk0 = *(const uint4*)srck;
            nk1 = *(const uint4*)(srck + 8);
            const f16_t* srcv = vtp + (size_t)rr * SEQ + kbase + 64 + cc;
            nv0 = *(const uint4*)srcv;
            nv1 = *(const uint4*)(srcv + 8);
            if (tid < 64) nm = mp[kbase + 64 + tid];
        }

        // ---- QK^T + p = exp(s)*invl -> p_all ----
        #pragma unroll
        for (int nt = 0; nt < 4; ++nt) {
            const f16x8 a0 = *(const f16x8*)&Kh[cur][nt*16 + l15][g4*8];
            const f16x8 a1 = *(const f16x8*)&Kh[cur][nt*16 + l15][32 + g4*8];
            const f32x4 mb = *(const f32x4*)&mask_s[cur][nt*16 + g4*4];
            __builtin_amdgcn_s_setprio(1);
            f32x4 c = {0.f, 0.f, 0.f, 0.f};
            c = MFMA16(a0, qf0, c);
            c = MFMA16(a1, qf1, c);
            __builtin_amdgcn_s_setprio(0);
            f32x4 pv;
            #pragma unroll
            for (int r = 0; r < 4; ++r)
                pv[r] = __expf(c[r] * 0.125f + mb[r] * (-1e9f)) * invl;
            *(f32x4*)&p_all[w*16 + l15][nt*16 + g4*4] = pv;
        }
        asm volatile("s_waitcnt lgkmcnt(0)" ::: "memory");
        __builtin_amdgcn_sched_barrier(0);

        // ---- PV: ctx^T[d][q] += V^T[d][k] P^T[k][q] ----
        #pragma unroll
        for (int kk = 0; kk < 2; ++kk) {
            const float* pr = &p_all[w*16 + l15][kk*32 + g4*8];
            const f32x4 p0 = *(const f32x4*)pr;
            const f32x4 p1 = *(const f32x4*)(pr + 4);
            f16x8 pf;
            #pragma unroll
            for (int j = 0; j < 4; ++j) { pf[j] = (f16_t)p0[j]; pf[j+4] = (f16_t)p1[j]; }
            __builtin_amdgcn_s_setprio(1);
            #pragma unroll
            for (int nt = 0; nt < 4; ++nt) {
                const f16x8 vf = *(const f16x8*)&Vt[cur][nt*16 + l15][kk*32 + g4*8];
                cacc[nt] = MFMA16(vf, pf, cacc[nt]);
            }
            __builtin_amdgcn_s_setprio(0);
        }

        // ---- attn store: full-line coalesced (16 lanes = 256B contiguous) ----
        #pragma unroll
        for (int j = 0; j < 4; ++j) {
            const int qloc = j*4 + g4;
            const f32x4 pv = *(const f32x4*)&p_all[w*16 + qloc][l15*4];
            __builtin_nontemporal_store(
                pv, (f32x4*)(attn_p + (size_t)(qw + qloc) * SEQ + kbase + l15*4));
        }

        if (have) {
            *(uint4*)&Kh[cur ^ 1][rr][cc]     = nk0;
            *(uint4*)&Kh[cur ^ 1][rr][cc + 8] = nk1;
            *(uint4*)&Vt[cur ^ 1][rr][cc]     = nv0;
            *(uint4*)&Vt[cur ^ 1][rr][cc + 8] = nv1;
            if (tid < 64) mask_s[cur ^ 1][tid] = nm;
        }
        LDS_SYNC();
        cur ^= 1;
    }

    // ---- epilogue: transpose ctx^T -> ctx via LDS ----
    #pragma unroll
    for (int nt = 0; nt < 4; ++nt)
        #pragma unroll
        for (int r = 0; r < 4; ++r)
            cx[nt*16 + g4*4 + r][w*16 + l15] = cacc[nt][r];
    LDS_SYNC();
    {
        const int q = tid >> 2, dc = (tid & 3) << 4;
        f16x8 o0, o1;
        #pragma unroll
        for (int j = 0; j < 8; ++j) {
            o0[j] = (f16_t)cx[dc + j][q];
            o1[j] = (f16_t)cx[dc + 8 + j][q];
        }
        f16_t* dst = ctxf + ((size_t)(b * SEQ) + qb + q) * DIM + h * 64 + dc;
        *(f16x8*)dst = o0;
        *(f16x8*)(dst + 8) = o1;
    }
}

// ---------------------------------------------------------------------------
// Kernel 4: out = ctx @ Wo + bo, direct-global MFMA (fp16).
// grid 256 (64 mb x 4 nb), block 256 (4 waves 2x2, 32x64 per wave)
// ---------------------------------------------------------------------------
__global__ __launch_bounds__(256, 2) void out_gemm_kernel(
    const f16_t* __restrict__ ctxf, const f16_t* __restrict__ wot,
    const float* __restrict__ bo, float* __restrict__ out)
{
    const int bx = blockIdx.x;
    const int mb = bx & 63, nb = bx >> 6;
    const int tid = threadIdx.x;
    const int w = tid >> 6, lane = tid & 63, l15 = lane & 15, g4 = lane >> 4;
    const int mBase = mb * 64 + (w >> 1) * 32;
    const int nBase = nb * 128 + (w & 1) * 64;

    f32x4 acc[2][4];
    #pragma unroll
    for (int i = 0; i < 2; ++i)
        #pragma unroll
        for (int j = 0; j < 4; ++j) acc[i][j] = (f32x4){0.f, 0.f, 0.f, 0.f};

    for (int k0 = 0; k0 < DIM; k0 += 64) {
        f16x8 ah[2][2];
        #pragma unroll
        for (int mt = 0; mt < 2; ++mt) {
            const f16_t* ar = ctxf + (size_t)(mBase + mt*16 + l15) * DIM + k0 + g4*8;
            ah[mt][0] = *(const f16x8*)ar;
            ah[mt][1] = *(const f16x8*)(ar + 32);
        }
        #pragma unroll
        for (int nt = 0; nt < 4; ++nt) {
            const f16_t* wr = wot + (size_t)(nBase + nt*16 + l15) * DIM + k0 + g4*8;
            #pragma unroll
            for (int kk = 0; kk < 2; ++kk) {
                f16x8 bw = *(const f16x8*)(wr + kk*32);
                #pragma unroll
                for (int mt = 0; mt < 2; ++mt)
                    acc[mt][nt] = MFMA16(ah[mt][kk], bw, acc[mt][nt]);
            }
        }
    }
    #pragma unroll
    for (int mt = 0; mt < 2; ++mt) {
        #pragma unroll
        for (int nt = 0; nt < 4; ++nt) {
            const int n = nBase + nt*16 + l15;
            const float bn = bo[n];
            #pragma unroll
            for (int r = 0; r < 4; ++r) {
                const int m = mBase + mt*16 + g4*4 + r;
                out[(size_t)m * DIM + n] = acc[mt][nt][r] + bn;
            }
        }
    }
}

// ---------------------------------------------------------------------------
extern "C" void kernel_launch(void* const* d_in, const int* in_sizes, int n_in,
                              void* d_out, int out_size, void* d_ws, size_t ws_size,
                              hipStream_t stream)
{
    const float* X    = (const float*)d_in[0];
    const float* mask = (const float*)d_in[1];
    const float* Wq   = (const float*)d_in[2];
    const float* bq   = (const float*)d_in[3];
    const float* Wk   = (const float*)d_in[4];
    const float* bk   = (const float*)d_in[5];
    const float* Wv   = (const float*)d_in[6];
    const float* bv   = (const float*)d_in[7];
    const float* Wo   = (const float*)d_in[8];
    const float* bo   = (const float*)d_in[9];

    float* out  = (float*)d_out;                          // [B,S,DIM]
    float* attn = out + (size_t)NB * SEQ * DIM;           // [B,H,S,S]

    const size_t N = (size_t)NB * NH * SEQ * DEPTH;       // 2,097,152
    f16_t* q_h  = (f16_t*)d_ws;
    f16_t* k_h  = q_h + N;
    f16_t* v_t  = k_h + N;
    f16_t* wt   = v_t + N;                                // [1536][512]
    f16_t* wot  = wt + (size_t)3 * DIM * DIM;             // [512][512]
    f16_t* ctxf = wot + (size_t)DIM * DIM;                // [B*S][DIM]
    f16_t* xh   = ctxf + N;                               // [B*S][DIM] fp16 X

    prep_kernel<<<1280, 256, 0, stream>>>(X, Wq, Wk, Wv, Wo, wt, wot, xh);

    qkv_gemm_kernel<<<768, 256, 0, stream>>>(xh, wt, bq, bk, bv, q_h, k_h, v_t);

    attn_kernel<<<512, 256, 0, stream>>>(q_h, k_h, v_t, mask, attn, ctxf);

    out_gemm_kernel<<<256, 256, 0, stream>>>(ctxf, wot, bo, out);
}

// Round 16
// 149.803 us; speedup vs baseline: 1.1932x; 1.0102x over previous
//
#include <hip/hip_runtime.h>
#include <cmath>

#define NB 2
#define SEQ 2048
#define DIM 512
#define NH 8
#define DEPTH 64
#define NT (SEQ / 64)

typedef _Float16 f16_t;
typedef _Float16 f16x4 __attribute__((ext_vector_type(4)));
typedef _Float16 f16x8 __attribute__((ext_vector_type(8)));
typedef float f32x4 __attribute__((ext_vector_type(4)));

#define MFMA16(a, b, c) __builtin_amdgcn_mfma_f32_16x16x32_f16((a), (b), (c), 0, 0, 0)

// LDS-visibility barrier: waits LDS ops only, never drains vmcnt.
#define LDS_SYNC() asm volatile("s_waitcnt lgkmcnt(0)\n\ts_barrier" ::: "memory")

// ---------------------------------------------------------------------------
// Kernel 1: prep — W^T as fp16 (bx<256) + X -> fp16 (bx>=256). grid 1280.
// ---------------------------------------------------------------------------
__global__ __launch_bounds__(256) void prep_kernel(
    const float* __restrict__ X,
    const float* __restrict__ Wq, const float* __restrict__ Wk,
    const float* __restrict__ Wv, const float* __restrict__ Wo,
    f16_t* __restrict__ wt, f16_t* __restrict__ wot, f16_t* __restrict__ xh)
{
    const int bx = blockIdx.x;
    if (bx >= 256) {
        const size_t i = ((size_t)(bx - 256) * 256 + threadIdx.x) * 8;
        const f32x4 a = *(const f32x4*)(X + i);
        const f32x4 b = *(const f32x4*)(X + i + 4);
        f16x8 o;
        #pragma unroll
        for (int j = 0; j < 4; ++j) { o[j] = (f16_t)a[j]; o[j+4] = (f16_t)b[j]; }
        *(f16x8*)(xh + i) = o;
        return;
    }
    __shared__ float Ws[64][68];
    const int z  = bx >> 6;
    const int kt = (bx >> 3) & 7;
    const int nt = bx & 7;
    const float* W = (z == 0) ? Wq : (z == 1) ? Wk : (z == 2) ? Wv : Wo;
    const int k0 = kt * 64, n0 = nt * 64;
    const int t = threadIdx.x;
    {
        const int r = t >> 2, c0 = (t & 3) * 16;
        #pragma unroll
        for (int j = 0; j < 4; ++j)
            *(f32x4*)&Ws[r][c0 + j*4] =
                *(const f32x4*)&W[(size_t)(k0 + r) * DIM + n0 + c0 + j*4];
    }
    __syncthreads();
    const int n = t >> 2, kc = (t & 3) * 16;
    f16x8 b0, b1;
    #pragma unroll
    for (int j = 0; j < 8; ++j) {
        b0[j] = (f16_t)Ws[kc + j][n];
        b1[j] = (f16_t)Ws[kc + 8 + j][n];
    }
    f16_t* dst = (z < 3) ? (wt + ((size_t)(z * DIM + n0 + n)) * DIM + k0 + kc)
                         : (wot + (size_t)(n0 + n) * DIM + k0 + kc);
    *(f16x8*)dst = b0;
    *(f16x8*)(dst + 8) = b1;
}

// ---------------------------------------------------------------------------
// Kernel 2: QKV projection, direct-global MFMA GEMM on fp16 X.
// 128x64 block tile, grid 768 (32 mb x 24 nb) = 3 blocks/CU.
// ---------------------------------------------------------------------------
__global__ __launch_bounds__(256, 2) void qkv_gemm_kernel(
    const f16_t* __restrict__ xh, const f16_t* __restrict__ wt,
    const float* __restrict__ bq, const float* __restrict__ bk,
    const float* __restrict__ bv,
    f16_t* __restrict__ q_h, f16_t* __restrict__ k_h, f16_t* __restrict__ v_t)
{
    const int bx = blockIdx.x;
    const int mb = bx & 31, nb = bx >> 5;          // 32 mb x 24 nb
    const int tid = threadIdx.x;
    const int w = tid >> 6, lane = tid & 63, l15 = lane & 15, g4 = lane >> 4;
    const int mBase = mb * 128 + (w >> 1) * 64;
    const int nBase = nb * 64 + (w & 1) * 32;

    f32x4 acc[4][2];
    #pragma unroll
    for (int i = 0; i < 4; ++i)
        #pragma unroll
        for (int j = 0; j < 2; ++j) acc[i][j] = (f32x4){0.f, 0.f, 0.f, 0.f};

    for (int k0 = 0; k0 < DIM; k0 += 64) {
        f16x8 ah[4][2];
        #pragma unroll
        for (int mt = 0; mt < 4; ++mt) {
            const f16_t* xr = xh + (size_t)(mBase + mt*16 + l15) * DIM + k0 + g4*8;
            ah[mt][0] = *(const f16x8*)xr;
            ah[mt][1] = *(const f16x8*)(xr + 32);
        }
        #pragma unroll
        for (int nt = 0; nt < 2; ++nt) {
            const f16_t* wr = wt + (size_t)(nBase + nt*16 + l15) * DIM + k0 + g4*8;
            #pragma unroll
            for (int kk = 0; kk < 2; ++kk) {
                f16x8 bw = *(const f16x8*)(wr + kk*32);
                #pragma unroll
                for (int mt = 0; mt < 4; ++mt)
                    acc[mt][nt] = MFMA16(ah[mt][kk], bw, acc[mt][nt]);
            }
        }
    }

    const int z = nb >> 3;                          // 8 nb-blocks per matrix
    const float* bias = (z == 0) ? bq : (z == 1) ? bk : bv;
    #pragma unroll
    for (int mt = 0; mt < 4; ++mt) {
        #pragma unroll
        for (int nt = 0; nt < 2; ++nt) {
            const int n = nBase + nt*16 + l15;      // 0..1535
            const int col = n & 511;
            const int h = (n >> 6) & 7, d = n & 63;
            const float bb = bias[col];
            #pragma unroll
            for (int r = 0; r < 4; ++r) {
                const int m = mBase + mt*16 + g4*4 + r;
                const int b = m >> 11, s = m & (SEQ - 1);
                const int bh = b * NH + h;
                const float v = acc[mt][nt][r] + bb;
                if (z == 2) {
                    v_t[((size_t)bh * DEPTH + d) * SEQ + s] = (f16_t)v;
                } else {
                    const size_t o = ((size_t)bh * SEQ + s) * DEPTH + d;
                    if (z == 0) q_h[o] = (f16_t)v;
                    else        k_h[o] = (f16_t)v;
                }
            }
        }
    }
}

// ---------------------------------------------------------------------------
// Kernel 3: fused two-pass flash attention — r15 champion, ONE change:
// P staged in LDS as f16 (Ph). PV consumed f16(p) already -> out path
// bit-identical; attn store gains <=2^-11 rounding (15x under threshold).
// Halves P LDS bytes; P-write/readback bank conflicts 8-way -> 4-way;
// LDS 54.8 -> 46.6 KB.
//  - no-max softmax; lgkm-only barriers; pass 0 = 128-key dbuf K tiles
//  - swapped-operand QK^T: mfma(K, Q) -> lane q = l15, keys = nt*16+g4*4+r
//  - attn written via Ph readback (f16->f32 cvt), full-line mapping
// grid 512 = 16 bh x 32 qt (XCD-swizzled), block 256 = 4 waves x 16 q-rows.
// ---------------------------------------------------------------------------
__global__ __launch_bounds__(256, 2) void attn_kernel(
    const f16_t* __restrict__ q_h, const f16_t* __restrict__ k_h,
    const f16_t* __restrict__ v_t, const float* __restrict__ mask,
    float* __restrict__ attn, f16_t* __restrict__ ctxf)
{
    __shared__ __align__(16) unsigned char smem[46592];
    f16_t (*Kh)[64][72] = (f16_t(*)[64][72])smem;            // 2 x 9216 B
    f16_t (*Vt)[64][72] = (f16_t(*)[64][72])(smem + 18432);  // 2 x 9216 B
    f16_t (*Ph)[72]     = (f16_t(*)[72])(smem + 36864);      // [64][72] f16
    float (*mask_s)[64] = (float(*)[64])(smem + 46080);      // 2 x 64 f32
    float (*cx)[68]     = (float(*)[68])smem;                // epilogue overlay
    // pass-0 overlays (V/Ph regions free in pass 0):
    f16_t (*K2)[128][72] = (f16_t(*)[128][72])smem;          // 2 x 18432 B
    float (*mask2)[128]  = (float(*)[128])(smem + 36864);    // 2 x 512 B

    const int tid = threadIdx.x;
    const int w = tid >> 6, lane = tid & 63;
    const int l15 = lane & 15, g4 = lane >> 4;
    const int rr = tid >> 2;              // 64-row staging: row, 0..63
    const int cc = (tid & 3) << 4;        // 64-row staging: col f16, 0/16/32/48
    const int r2 = tid >> 1;              // 128-row staging: row, 0..127
    const int c2 = (tid & 1) << 5;        // 128-row staging: col f16, 0/32

    const int id  = blockIdx.x;
    const int nid = (id & 7) * 64 + (id >> 3);            // XCD-contiguous
    const int bh = nid >> 5, qt = nid & 31;
    const int b = bh >> 3, h = bh & 7;

    const size_t kvb = (size_t)bh * SEQ * DEPTH;
    const f16_t* khp = k_h + kvb;
    const f16_t* vtp = v_t + kvb;                         // [64][SEQ]
    const float* mp  = mask + b * SEQ;
    float* attn_p = attn + (size_t)bh * SEQ * SEQ;

    const int qb = qt * 64;
    const int qw = qb + w * 16;

    // Q fragment (B-operand: lane l15 = q row, g4*8 = d chunk)
    f16x8 qf0, qf1;
    {
        const f16_t* qr = q_h + kvb + (size_t)(qw + l15) * DEPTH + g4 * 8;
        qf0 = *(const f16x8*)qr;
        qf1 = *(const f16x8*)(qr + 32);
    }

    float l_r = 0.f;

    // ====== pass 0: sum(exp), 128-key double-buffered K tiles ======
    {
        const f16_t* s0 = khp + (size_t)r2 * DEPTH + c2;
        *(uint4*)&K2[0][r2][c2]      = *(const uint4*)s0;
        *(uint4*)&K2[0][r2][c2 + 8]  = *(const uint4*)(s0 + 8);
        *(uint4*)&K2[0][r2][c2 + 16] = *(const uint4*)(s0 + 16);
        *(uint4*)&K2[0][r2][c2 + 24] = *(const uint4*)(s0 + 24);
        if (tid < 128) mask2[0][tid] = mp[tid];
    }
    LDS_SYNC();

    int cur = 0;
    for (int kt = 0; kt < NT / 2; ++kt) {
        const bool have = (kt + 1) < NT / 2;
        uint4 nk[4]; float nm = 0.f;
        if (have) {
            const f16_t* src = khp + (size_t)((kt+1)*128 + r2) * DEPTH + c2;
            nk[0] = *(const uint4*)src;
            nk[1] = *(const uint4*)(src + 8);
            nk[2] = *(const uint4*)(src + 16);
            nk[3] = *(const uint4*)(src + 24);
            if (tid < 128) nm = mp[(kt+1)*128 + tid];
        }

        #pragma unroll
        for (int nt = 0; nt < 8; ++nt) {
            const f16x8 a0 = *(const f16x8*)&K2[cur][nt*16 + l15][g4*8];
            const f16x8 a1 = *(const f16x8*)&K2[cur][nt*16 + l15][32 + g4*8];
            const f32x4 mb = *(const f32x4*)&mask2[cur][nt*16 + g4*4];
            __builtin_amdgcn_s_setprio(1);
            f32x4 c = {0.f, 0.f, 0.f, 0.f};
            c = MFMA16(a0, qf0, c);
            c = MFMA16(a1, qf1, c);
            __builtin_amdgcn_s_setprio(0);
            #pragma unroll
            for (int r = 0; r < 4; ++r)
                l_r += __expf(c[r] * 0.125f + mb[r] * (-1e9f));
        }

        if (have) {
            *(uint4*)&K2[cur ^ 1][r2][c2]      = nk[0];
            *(uint4*)&K2[cur ^ 1][r2][c2 + 8]  = nk[1];
            *(uint4*)&K2[cur ^ 1][r2][c2 + 16] = nk[2];
            *(uint4*)&K2[cur ^ 1][r2][c2 + 24] = nk[3];
            if (tid < 128) mask2[cur ^ 1][tid] = nm;
        }
        LDS_SYNC();
        cur ^= 1;
    }
    // deferred cross-lane reduce (sum is linear; no max tracking)
    l_r += __shfl_xor(l_r, 16);
    l_r += __shfl_xor(l_r, 32);
    const float invl = 1.0f / l_r;

    f32x4 cacc[4];
    #pragma unroll
    for (int nt = 0; nt < 4; ++nt) cacc[nt] = (f32x4){0.f, 0.f, 0.f, 0.f};

    // ================= pass 1: recompute, write attn, PV =================
    {
        const f16_t* s0 = khp + (size_t)rr * DEPTH + cc;
        *(uint4*)&Kh[0][rr][cc]     = *(const uint4*)s0;
        *(uint4*)&Kh[0][rr][cc + 8] = *(const uint4*)(s0 + 8);
        const f16_t* s1 = vtp + (size_t)rr * SEQ + cc;
        *(uint4*)&Vt[0][rr][cc]     = *(const uint4*)s1;
        *(uint4*)&Vt[0][rr][cc + 8] = *(const uint4*)(s1 + 8);
        if (tid < 64) mask_s[0][tid] = mp[tid];
    }
    LDS_SYNC();

    cur = 0;
    for (int kt = 0; kt < NT; ++kt) {
        const int kbase = kt * 64;
        const bool have = (kt + 1) < NT;
        uint4 nk0, nk1, nv0, nv1; float nm = 0.f;
        if (have) {
            const f16_t* srck = khp + (size_t)(kbase + 64 + rr) * DEPTH + cc;
            nk0 = *(const uint4*)srck;
            nk1 = *(const uint4*)(srck + 8);
            const f16_t* srcv = vtp + (size_t)rr * SEQ + kbase + 64 + cc;
            nv0 = *(const uint4*)srcv;
            nv1 = *(const uint4*)(srcv + 8);
            if (tid < 64) nm = mp[kbase + 64 + tid];
        }

        // ---- QK^T + p = f16(exp(s)*invl) -> Ph ----
        #pragma unroll
        for (int nt = 0; nt < 4; ++nt) {
            const f16x8 a0 = *(const f16x8*)&Kh[cur][nt*16 + l15][g4*8];
            const f16x8 a1 = *(const f16x8*)&Kh[cur][nt*16 + l15][32 + g4*8];
            const f32x4 mb = *(const f32x4*)&mask_s[cur][nt*16 + g4*4];
            __builtin_amdgcn_s_setprio(1);
            f32x4 c = {0.f, 0.f, 0.f, 0.f};
            c = MFMA16(a0, qf0, c);
            c = MFMA16(a1, qf1, c);
            __builtin_amdgcn_s_setprio(0);
            f16x4 pc;
            #pragma unroll
            for (int r = 0; r < 4; ++r)
                pc[r] = (f16_t)(__expf(c[r] * 0.125f + mb[r] * (-1e9f)) * invl);
            *(f16x4*)&Ph[w*16 + l15][nt*16 + g4*4] = pc;
        }
        asm volatile("s_waitcnt lgkmcnt(0)" ::: "memory");
        __builtin_amdgcn_sched_barrier(0);

        // ---- PV: ctx^T[d][q] += V^T[d][k] P^T[k][q] (P read direct f16) ----
        #pragma unroll
        for (int kk = 0; kk < 2; ++kk) {
            const f16x8 pf = *(const f16x8*)&Ph[w*16 + l15][kk*32 + g4*8];
            __builtin_amdgcn_s_setprio(1);
            #pragma unroll
            for (int nt = 0; nt < 4; ++nt) {
                const f16x8 vf = *(const f16x8*)&Vt[cur][nt*16 + l15][kk*32 + g4*8];
                cacc[nt] = MFMA16(vf, pf, cacc[nt]);
            }
            __builtin_amdgcn_s_setprio(0);
        }

        // ---- attn store: readback f16 -> f32, full-line coalesced ----
        #pragma unroll
        for (int j = 0; j < 4; ++j) {
            const int qloc = j*4 + g4;
            const f16x4 ph4 = *(const f16x4*)&Ph[w*16 + qloc][l15*4];
            f32x4 pv;
            #pragma unroll
            for (int t = 0; t < 4; ++t) pv[t] = (float)ph4[t];
            __builtin_nontemporal_store(
                pv, (f32x4*)(attn_p + (size_t)(qw + qloc) * SEQ + kbase + l15*4));
        }

        if (have) {
            *(uint4*)&Kh[cur ^ 1][rr][cc]     = nk0;
            *(uint4*)&Kh[cur ^ 1][rr][cc + 8] = nk1;
            *(uint4*)&Vt[cur ^ 1][rr][cc]     = nv0;
            *(uint4*)&Vt[cur ^ 1][rr][cc + 8] = nv1;
            if (tid < 64) mask_s[cur ^ 1][tid] = nm;
        }
        LDS_SYNC();
        cur ^= 1;
    }

    // ---- epilogue: transpose ctx^T -> ctx via LDS ----
    #pragma unroll
    for (int nt = 0; nt < 4; ++nt)
        #pragma unroll
        for (int r = 0; r < 4; ++r)
            cx[nt*16 + g4*4 + r][w*16 + l15] = cacc[nt][r];
    LDS_SYNC();
    {
        const int q = tid >> 2, dc = (tid & 3) << 4;
        f16x8 o0, o1;
        #pragma unroll
        for (int j = 0; j < 8; ++j) {
            o0[j] = (f16_t)cx[dc + j][q];
            o1[j] = (f16_t)cx[dc + 8 + j][q];
        }
        f16_t* dst = ctxf + ((size_t)(b * SEQ) + qb + q) * DIM + h * 64 + dc;
        *(f16x8*)dst = o0;
        *(f16x8*)(dst + 8) = o1;
    }
}

// ---------------------------------------------------------------------------
// Kernel 4: out = ctx @ Wo + bo, direct-global MFMA (fp16).
// grid 256 (64 mb x 4 nb), block 256 (4 waves 2x2, 32x64 per wave)
// ---------------------------------------------------------------------------
__global__ __launch_bounds__(256, 2) void out_gemm_kernel(
    const f16_t* __restrict__ ctxf, const f16_t* __restrict__ wot,
    const float* __restrict__ bo, float* __restrict__ out)
{
    const int bx = blockIdx.x;
    const int mb = bx & 63, nb = bx >> 6;
    const int tid = threadIdx.x;
    const int w = tid >> 6, lane = tid & 63, l15 = lane & 15, g4 = lane >> 4;
    const int mBase = mb * 64 + (w >> 1) * 32;
    const int nBase = nb * 128 + (w & 1) * 64;

    f32x4 acc[2][4];
    #pragma unroll
    for (int i = 0; i < 2; ++i)
        #pragma unroll
        for (int j = 0; j < 4; ++j) acc[i][j] = (f32x4){0.f, 0.f, 0.f, 0.f};

    for (int k0 = 0; k0 < DIM; k0 += 64) {
        f16x8 ah[2][2];
        #pragma unroll
        for (int mt = 0; mt < 2; ++mt) {
            const f16_t* ar = ctxf + (size_t)(mBase + mt*16 + l15) * DIM + k0 + g4*8;
            ah[mt][0] = *(const f16x8*)ar;
            ah[mt][1] = *(const f16x8*)(ar + 32);
        }
        #pragma unroll
        for (int nt = 0; nt < 4; ++nt) {
            const f16_t* wr = wot + (size_t)(nBase + nt*16 + l15) * DIM + k0 + g4*8;
            #pragma unroll
            for (int kk = 0; kk < 2; ++kk) {
                f16x8 bw = *(const f16x8*)(wr + kk*32);
                #pragma unroll
                for (int mt = 0; mt < 2; ++mt)
                    acc[mt][nt] = MFMA16(ah[mt][kk], bw, acc[mt][nt]);
            }
        }
    }
    #pragma unroll
    for (int mt = 0; mt < 2; ++mt) {
        #pragma unroll
        for (int nt = 0; nt < 4; ++nt) {
            const int n = nBase + nt*16 + l15;
            const float bn = bo[n];
            #pragma unroll
            for (int r = 0; r < 4; ++r) {
                const int m = mBase + mt*16 + g4*4 + r;
                out[(size_t)m * DIM + n] = acc[mt][nt][r] + bn;
            }
        }
    }
}

// ---------------------------------------------------------------------------
extern "C" void kernel_launch(void* const* d_in, const int* in_sizes, int n_in,
                              void* d_out, int out_size, void* d_ws, size_t ws_size,
                              hipStream_t stream)
{
    const float* X    = (const float*)d_in[0];
    const float* mask = (const float*)d_in[1];
    const float* Wq   = (const float*)d_in[2];
    const float* bq   = (const float*)d_in[3];
    const float* Wk   = (const float*)d_in[4];
    const float* bk   = (const float*)d_in[5];
    const float* Wv   = (const float*)d_in[6];
    const float* bv   = (const float*)d_in[7];
    const float* Wo   = (const float*)d_in[8];
    const float* bo   = (const float*)d_in[9];

    float* out  = (float*)d_out;                          // [B,S,DIM]
    float* attn = out + (size_t)NB * SEQ * DIM;           // [B,H,S,S]

    const size_t N = (size_t)NB * NH * SEQ * DEPTH;       // 2,097,152
    f16_t* q_h  = (f16_t*)d_ws;
    f16_t* k_h  = q_h + N;
    f16_t* v_t  = k_h + N;
    f16_t* wt   = v_t + N;                                // [1536][512]
    f16_t* wot  = wt + (size_t)3 * DIM * DIM;             // [512][512]
    f16_t* ctxf = wot + (size_t)DIM * DIM;                // [B*S][DIM]
    f16_t* xh   = ctxf + N;                               // [B*S][DIM] fp16 X

    prep_kernel<<<1280, 256, 0, stream>>>(X, Wq, Wk, Wv, Wo, wt, wot, xh);

    qkv_gemm_kernel<<<768, 256, 0, stream>>>(xh, wt, bq, bk, bv, q_h, k_h, v_t);

    attn_kernel<<<512, 256, 0, stream>>>(q_h, k_h, v_t, mask, attn, ctxf);

    out_gemm_kernel<<<256, 256, 0, stream>>>(ctxf, wot, bo, out);
}